// Round 9
// baseline (292.467 us; speedup 1.0000x reference)
//
#include <hip/hip_runtime.h>
#include <hip/hip_bf16.h>

typedef __attribute__((ext_vector_type(8))) short short8;
typedef __attribute__((ext_vector_type(4))) short short4_t;
typedef __attribute__((ext_vector_type(4))) float floatx4;

// ---------------- workspace layout (float offsets) ----------------
#define OFF_B1P   0        // conv1 B frags [7][64][8] bf16
#define OFF_B2P   1792     // conv2 B frags [2][14][64][8] bf16
#define OFF_B3P   8960     // conv3 B frags [4][27][64][8] bf16
#define OFF_WIHT  36608    // w_init_h^T  (64,256)
#define OFF_WIH1T 52992    // wih1^T      (64,256)
#define OFF_WI2B  69376    // w_init_h2 bf16 row-major [t][k] (reuses old wi2t slot)
#define OFF_WHH1B 134912   // whh1 bf16 row-major [t][k]
#define OFF_WIH2B 167680   // wih2 bf16 row-major
#define OFF_WHH2B 200448   // whh2 bf16 row-major
#define OFF_WL1P  233216   // w_lin1 MFMA frags [nt16][c162][lane64][j8] bf16
#define OFF_ME    896768   // mean_enc (512,64)
#define OFF_H0BF  929536   // h0 bf16 [512][256] (reuses old fp32 h slot)
#define OFF_H2    1060608  // h2_0(512,256) fp32
#define OFF_IHC   1191680  // ih_const (512,256)
#define OFF_P1    1322752  // p1 bf16 [512][1296][16]
#define OFF_T1    1322752  // lin1 partials 8x(512,256) fp32 (over dead p1)
#define OFF_Y     2377728  // y = Hseq@wih2^T + b2, f32 [23*512][256] (over dead p1)
#define OFF_HSEQ  5392384  // h_1..h_23 bf16 [23*512][256] (over dead p1/p2)
#define OFF_P2    6631168  // p2 bf16 [512][324][32]
#define OFF_P3BF  9285376  // p3 bf16 [512][5184]

#define S2_H 88
#define S2_D 1760
#define S3_H 88
#define S3_D 1760
#define S3_HALF 14080

static __device__ inline short f2bf(float f) {
  union { __hip_bfloat16 h; short s; } u;
  u.h = __float2bfloat16(f);
  return u.s;
}
static __device__ inline float bf2f(short s) {
  union { unsigned u; float f; } v;
  v.u = ((unsigned)(unsigned short)s) << 16;
  return v.f;
}
// 5-instr tanh: 1 - 2/(e^{2x}+1); inf-safe both directions
static __device__ inline float fast_tanh(float x) {
  float e = __expf(2.f * x);
  return __builtin_fmaf(-2.f, __builtin_amdgcn_rcpf(e + 1.f), 1.f);
}

// ---------------- prep: weight frag packs + RNN packs ----------------
__global__ __launch_bounds__(256) void prep_kernel(
    const float* __restrict__ w1, const float* __restrict__ w2, const float* __restrict__ w3,
    const float* __restrict__ w_init_h, const float* __restrict__ wih1,
    const float* __restrict__ w_init_h2, const float* __restrict__ whh1,
    const float* __restrict__ wih2, const float* __restrict__ whh2,
    float* __restrict__ ws) {
  int i = blockIdx.x * 256 + threadIdx.x;
  if (i < 3584) {
    int j = i & 7, l = (i >> 3) & 63, c = i >> 9;
    int k = c*32 + ((l >> 4) << 3) + j;
    int tap = k >> 3, icp = k & 7, oc = l & 15;
    float v = (tap < 27 && icp < 6) ? w1[(oc*6 + icp)*27 + tap] : 0.f;
    ((__hip_bfloat16*)(ws + OFF_B1P))[i] = __float2bfloat16(v);
    return;
  }
  i -= 3584;
  if (i < 14336) {
    int j = i & 7, l = (i >> 3) & 63, cc = i >> 9;
    int c = cc % 14, nt = cc / 14;
    int k = c*32 + ((l >> 4) << 3) + j;
    int tap = k >> 4, ic = k & 15, oc = nt*16 + (l & 15);
    float v = (tap < 27) ? w2[(oc*16 + ic)*27 + tap] : 0.f;
    ((__hip_bfloat16*)(ws + OFF_B2P))[i] = __float2bfloat16(v);
    return;
  }
  i -= 14336;
  if (i < 55296) {
    int j = i & 7, l = (i >> 3) & 63, cc = i >> 9;
    int c = cc % 27, nt = cc / 27;
    int k = c*32 + ((l >> 4) << 3) + j;
    int ic = k & 31, oc = nt*16 + (l & 15);
    ((__hip_bfloat16*)(ws + OFF_B3P))[i] = __float2bfloat16(w3[(oc*32 + ic)*27 + c]);
    return;
  }
  i -= 55296;
  if (i < 16384) { int t = i & 255, k = i >> 8; ws[OFF_WIHT + i]  = w_init_h[t*64 + k];  return; }
  i -= 16384;
  if (i < 16384) { int t = i & 255, k = i >> 8; ws[OFF_WIH1T + i] = wih1[t*64 + k];      return; }
  i -= 16384;
  if (i < 65536) { ((__hip_bfloat16*)(ws + OFF_WI2B))[i] = __float2bfloat16(w_init_h2[i]); return; }
  i -= 65536;
  if (i < 65536) { ((__hip_bfloat16*)(ws + OFF_WHH1B))[i] = __float2bfloat16(whh1[i]); return; }
  i -= 65536;
  if (i < 65536) { ((__hip_bfloat16*)(ws + OFF_WIH2B))[i] = __float2bfloat16(wih2[i]); return; }
  i -= 65536;
  if (i < 65536) { ((__hip_bfloat16*)(ws + OFF_WHH2B))[i] = __float2bfloat16(whh2[i]); return; }
}

// ---------------- conv1 MFMA + w_lin1 pack tail blocks ----------------
// R8: (1) 16B-slot XOR swizzle s^=(s>>3)&7 on slab writes AND reads — the
// quad's 16 A-read slots piled 4-way into bank-group 2 (dd=+370, dh=+5, w=+1
// mod 8); swizzle decorrelates to ~2-way (free per m136). base+tapoff
// decomposes exactly into a valid (d,h,w) slot (h<74, w<5: no carry), so
// swizzling the summed slot is correct. Zero-fill is bijective -> unchanged.
// (2) pack arm vectorized 8x: 648 blocks, 2 float4 loads + 1 short8 write per
// thread (was 5184 blocks of scalar dribble sharing this dispatch).
__global__ __launch_bounds__(256) void conv1_mfma(
    const float* __restrict__ x, const short* __restrict__ b1p,
    const float* __restrict__ bias, short* __restrict__ p1,
    const float* __restrict__ w_lin1, short* __restrict__ wl1p) {
  __shared__ __align__(16) short slab[8 * 74 * 5 * 8];
  int tid = threadIdx.x;
  if (blockIdx.x >= 2048) {
    int u = (blockIdx.x - 2048)*256 + tid;   // [0, 165888)
    int l = u & 63, cc = u >> 6;
    int c = cc % 162, nt = cc / 162;
    int n = nt*16 + (l & 15);
    int k0 = c*32 + ((l >> 4) << 3);
    const float* src = w_lin1 + (size_t)n*5184 + k0;
    float4 v0 = *(const float4*)src;
    float4 v1 = *(const float4*)(src + 4);
    short8 s;
    s[0] = f2bf(v0.x); s[1] = f2bf(v0.y); s[2] = f2bf(v0.z); s[3] = f2bf(v0.w);
    s[4] = f2bf(v1.x); s[5] = f2bf(v1.y); s[6] = f2bf(v1.z); s[7] = f2bf(v1.w);
    *(short8*)(wl1p + (size_t)u*8) = s;
    return;
  }
  int b = blockIdx.x >> 2, q = blockIdx.x & 3;
  short8 z8 = {0,0,0,0,0,0,0,0};
  for (int i = tid; i < 2960; i += 256) *(short8*)(slab + i*8) = z8;
  __syncthreads();
  #pragma unroll
  for (int base = 0; base < 432; base += 256) {
    int u = base + tid;
    if (u < 432) {
      int dslot = u / 54;
      int g = u - dslot*54;
      int d = 6*q - 1 + dslot;
      if ((unsigned)d < 24u) {
        float4 v[6];
        #pragma unroll
        for (int ic = 0; ic < 6; ++ic)
          v[ic] = *(const float4*)(x + ((size_t)(b*6 + ic)*24 + d)*216 + g*4);
        const float* vv = (const float*)v;
        #pragma unroll
        for (int e = 0; e < 4; ++e) {
          int p = g*4 + e;
          int h = p/3, w = p - h*3;
          short8 s = z8;
          #pragma unroll
          for (int ic = 0; ic < 6; ++ic) s[ic] = f2bf(vv[ic*4 + e]);
          int slot = dslot*370 + (1 + h)*5 + (1 + w);
          slot ^= (slot >> 3) & 7;
          *(short8*)(slab + slot*8) = s;
        }
      }
    }
  }
  int lane = tid & 63, wid = tid >> 6;
  int quad = lane >> 4, col = lane & 15;
  short8 bf[7];
  #pragma unroll
  for (int c = 0; c < 7; ++c) bf[c] = *(const short8*)(b1p + (c*64 + lane)*8);
  int tapslot[7];
  #pragma unroll
  for (int c = 0; c < 7; ++c) {
    int tap = c*4 + quad;
    int tt = tap < 27 ? tap : 26;
    int kd = tt/9, rr = tt - kd*9, kh = rr/3, kw = rr - kh*3;
    tapslot[c] = (kd*74 + kh)*5 + kw;
  }
  float bv = bias[col];
  __syncthreads();
  for (int tile = wid; tile < 81; tile += 4) {
    int m = tile*16 + col;
    int dd = m & 1, dh = (m >> 1) & 1;
    int P = m >> 2;
    int t2 = P/3; int w = P - t2*3;
    int pdl = t2/36; int ph = t2 - pdl*36;
    int sbase = ((2*pdl + dd)*74 + 2*ph + dh)*5 + w;
    floatx4 acc = {0.f, 0.f, 0.f, 0.f};
    #pragma unroll
    for (int c = 0; c < 7; ++c) {
      int s = sbase + tapslot[c];
      s ^= (s >> 3) & 7;
      short8 af = *(const short8*)(slab + s*8);
      acc = __builtin_amdgcn_mfma_f32_16x16x32_bf16(af, bf[c], acc, 0, 0, 0);
    }
    float v = fmaxf(fmaxf(acc[0], acc[1]), fmaxf(acc[2], acc[3]));
    v = fmaxf(v + bv, 0.f);
    int Pout = q*324 + tile*4 + quad;
    p1[((size_t)b*1296 + Pout)*16 + col] = f2bf(v);
  }
}

// ---------------- conv2 MFMA, halo slab: p1 -> p2 bf16 [b][324][32] ----------------
__global__ __launch_bounds__(256) void conv2_mfma(
    const short* __restrict__ p1, const short* __restrict__ b2p,
    const float* __restrict__ bias2, short* __restrict__ p2g) {
  __shared__ __align__(16) short slab[14 * S2_D];
  int tid = threadIdx.x;
  int b = blockIdx.x >> 1, qh = blockIdx.x & 1;
  short8 z8 = {0,0,0,0,0,0,0,0};
  for (int i = tid; i < 3080; i += 256) *(short8*)(slab + i*8) = z8;
  __syncthreads();
  for (int i = tid; i < 1440; i += 256) {
    int c8 = i % 6; int r = i / 6; int hr = r % 20; int d = r / 20;
    int hg = 18*qh - 1 + hr;
    if ((unsigned)hg < 36u) {
      short8 v = *(const short8*)(p1 + ((size_t)b*1296 + (d*36 + hg)*3)*16 + c8*8);
      *(short8*)(slab + (d+1)*S2_D + hr*S2_H + 16 + c8*8) = v;
    }
  }
  int lane = tid & 63, wid = tid >> 6;
  int quad = lane >> 4, col = lane & 15;
  short8 bf[2][14];
  #pragma unroll
  for (int nt = 0; nt < 2; ++nt)
    #pragma unroll
    for (int c = 0; c < 14; ++c)
      bf[nt][c] = *(const short8*)(b2p + ((nt*14 + c)*64 + lane)*8);
  int tq = quad >> 1, icoff = (quad & 1) * 8;
  int tapoff[14];
  #pragma unroll
  for (int c = 0; c < 14; ++c) {
    int tap = 2*c + tq; if (tap > 26) tap = 26;
    int kd = tap/9, rr = tap - kd*9, kh = rr/3, kw = rr - kh*3;
    tapoff[c] = kd*S2_D + kh*S2_H + kw*16 + icoff;
  }
  float bv0 = bias2[col], bv1 = bias2[16 + col];
  __syncthreads();
  for (int tile = wid; tile < 41; tile += 4) {
    int m = tile*16 + col; if (m > 647) m = 647;
    int dd = m & 1, dh = (m >> 1) & 1;
    int P = m >> 2;
    int t = P/3; int w = P - t*3;
    int pd = t/9; int phl = t - pd*9;
    int base = (2*pd + dd)*S2_D + (2*phl + dh)*S2_H + w*16;
    floatx4 a0 = {0.f,0.f,0.f,0.f}, a1 = {0.f,0.f,0.f,0.f};
    #pragma unroll
    for (int c = 0; c < 14; ++c) {
      short8 a = *(const short8*)(slab + base + tapoff[c]);
      a0 = __builtin_amdgcn_mfma_f32_16x16x32_bf16(a, bf[0][c], a0, 0, 0, 0);
      a1 = __builtin_amdgcn_mfma_f32_16x16x32_bf16(a, bf[1][c], a1, 0, 0, 0);
    }
    int P2l = tile*4 + quad;
    if (P2l < 162) {
      float v0 = fmaxf(fmaxf(fmaxf(a0[0],a0[1]), fmaxf(a0[2],a0[3])) + bv0, 0.f);
      float v1 = fmaxf(fmaxf(fmaxf(a1[0],a1[1]), fmaxf(a1[2],a1[3])) + bv1, 0.f);
      int t2 = P2l/3; int w2 = P2l - t2*3;
      int pd2 = t2/9; int ph2 = t2 - pd2*9;
      size_t off = ((size_t)b*324 + (pd2*18 + 9*qh + ph2)*3 + w2)*32;
      p2g[off + col] = f2bf(v0);
      p2g[off + 16 + col] = f2bf(v1);
    }
  }
}

// ---------------- conv3 MFMA, dual ic-half halo slabs: p2 -> p3bf + mean ----------------
__global__ __launch_bounds__(256) void conv3_mfma(
    const short* __restrict__ p2g, const short* __restrict__ b3p,
    const float* __restrict__ bias3,
    short* __restrict__ p3bf, float* __restrict__ me) {
  __shared__ __align__(16) short slab[2 * S3_HALF];
  __shared__ float smean[4][32];
  int tid = threadIdx.x;
  int b = blockIdx.x;
  short8 z8 = {0,0,0,0,0,0,0,0};
  for (int i = tid; i < 3520; i += 256) *(short8*)(slab + i*8) = z8;
  __syncthreads();
  for (int i = tid; i < 1296; i += 256) {
    int c8 = i & 1;
    int hv = (i >> 1) & 1;
    int cell = i >> 2;
    int t = cell/3; int w = cell - t*3;
    int d = t/18; int h = t - d*18;
    short8 v = *(const short8*)(p2g + ((size_t)b*324 + cell)*32 + hv*16 + c8*8);
    *(short8*)(slab + hv*S3_HALF + (d+1)*S3_D + (h+1)*S3_H + (w+1)*16 + c8*8) = v;
  }
  int lane = tid & 63, wid = tid >> 6;
  int quad = lane >> 4, col = lane & 15;
  int ntp = (wid & 1) * 2;
  int tsel = wid >> 1;
  short8 bf[2][27];
  #pragma unroll
  for (int u = 0; u < 2; ++u)
    #pragma unroll
    for (int c = 0; c < 27; ++c)
      bf[u][c] = *(const short8*)(b3p + (((ntp+u)*27 + c)*64 + lane)*8);
  const short* sb = slab + (quad >> 1)*S3_HALF + (quad & 1)*8;
  float bva = bias3[ntp*16 + col], bvb = bias3[(ntp+1)*16 + col];
  float ms0 = 0.f, ms1 = 0.f;
  __syncthreads();
  for (int tile = tsel; tile < 21; tile += 2) {
    int m = tile*16 + col; if (m > 323) m = 323;
    int dd = m & 1, dh = (m >> 1) & 1;
    int P = m >> 2;
    int t = P/3; int w = P - t*3;
    int pd = t/9; int ph = t - pd*9;
    const short* ap = sb + (2*pd + dd)*S3_D + (2*ph + dh)*S3_H + w*16;
    floatx4 a0 = {0.f,0.f,0.f,0.f}, a1 = {0.f,0.f,0.f,0.f};
    #pragma unroll
    for (int c = 0; c < 27; ++c) {
      const int kd = c/9, rr = c - kd*9, kh = rr/3, kw = rr - kh*3;
      short8 a = *(const short8*)(ap + kd*S3_D + kh*S3_H + kw*16);
      a0 = __builtin_amdgcn_mfma_f32_16x16x32_bf16(a, bf[0][c], a0, 0, 0, 0);
      a1 = __builtin_amdgcn_mfma_f32_16x16x32_bf16(a, bf[1][c], a1, 0, 0, 0);
    }
    int Pout = tile*4 + quad;
    if (Pout < 81) {
      float v0 = fmaxf(fmaxf(fmaxf(a0[0],a0[1]), fmaxf(a0[2],a0[3])) + bva, 0.f);
      float v1 = fmaxf(fmaxf(fmaxf(a1[0],a1[1]), fmaxf(a1[2],a1[3])) + bvb, 0.f);
      size_t oi = ((size_t)b*81 + Pout)*64 + ntp*16 + col;
      p3bf[oi] = f2bf(v0);
      p3bf[oi + 16] = f2bf(v1);
      ms0 += v0; ms1 += v1;
    }
  }
  ms0 += __shfl_xor(ms0, 16, 64); ms0 += __shfl_xor(ms0, 32, 64);
  ms1 += __shfl_xor(ms1, 16, 64); ms1 += __shfl_xor(ms1, 32, 64);
  if (lane < 16) { smean[wid][lane] = ms0; smean[wid][16 + lane] = ms1; }
  __syncthreads();
  if (tid < 64) {
    float s = (tid < 32) ? (smean[0][tid] + smean[2][tid])
                         : (smean[1][tid-32] + smean[3][tid-32]);
    me[b*64 + tid] = s * (1.f / 81.f);
  }
}

// ---------------- init: h0 (bf16) + ihc only; K=64. 256 blocks x 2 rows -------
__global__ __launch_bounds__(256) void init_kernel(
    const float* __restrict__ me, const float* __restrict__ wiht,
    const float* __restrict__ b_init_h, const float* __restrict__ wih1t,
    const float* __restrict__ bih1, const float* __restrict__ bhh1,
    short* __restrict__ h0bf, float* __restrict__ ihcout) {
  __shared__ float sme[2][64];
  int t = threadIdx.x; int bb = blockIdx.x * 2;
  if (t < 128) sme[t >> 6][t & 63] = me[(bb + (t >> 6))*64 + (t & 63)];
  __syncthreads();
  float a0 = b_init_h[t], a1 = a0;
  float c0 = bih1[t] + bhh1[t], c1 = c0;
  #pragma unroll
  for (int k = 0; k < 64; ++k) {
    float w1v = wiht[k*256 + t], w2v = wih1t[k*256 + t];
    a0 += sme[0][k]*w1v; a1 += sme[1][k]*w1v;
    c0 += sme[0][k]*w2v; c1 += sme[1][k]*w2v;
  }
  h0bf[(size_t)bb*256 + t]     = f2bf(a0);
  h0bf[(size_t)(bb+1)*256 + t] = f2bf(a1);
  ihcout[(size_t)bb*256 + t]     = c0;
  ihcout[(size_t)(bb+1)*256 + t] = c1;
}

// ---------------- fusedA: blocks 0-31 t_h, 32-159 lin1, 160-167 h2_0 GEMM -----
__global__ __launch_bounds__(512) void fusedA(
    const short* __restrict__ h0bf, const float* __restrict__ ihc,
    const short* __restrict__ whh1b, short* __restrict__ hseq,
    const short* __restrict__ p3bf, const short* __restrict__ wl1p,
    const float* __restrict__ b_lin1, float* __restrict__ t1,
    const short* __restrict__ wi2b, const float* __restrict__ b_init_h2,
    float* __restrict__ h2out) {
  __shared__ __align__(16) short pool[23040];
  int tid = threadIdx.x;

  if (blockIdx.x >= 160) {
    // ---- h2_0 arm: 64 rows x 256 cols, K=256 ----
    short (*As)[72] = (short (*)[72])pool;              // [64][72]
    short (*Bs)[72] = (short (*)[72])(pool + 4608);     // [256][72]
    int lane = tid & 63, w = tid >> 6;
    int quad = lane >> 4, col = lane & 15;
    int m0 = (blockIdx.x - 160) * 64;
    int n0 = w * 32;
    float bv[2];
    #pragma unroll
    for (int t = 0; t < 2; ++t) bv[t] = b_init_h2[n0 + t*16 + col];
    floatx4 acc[4][2];
    #pragma unroll
    for (int ms = 0; ms < 4; ++ms)
      #pragma unroll
      for (int t = 0; t < 2; ++t)
        #pragma unroll
        for (int r = 0; r < 4; ++r) acc[ms][t][r] = bv[t];
    int arow = tid >> 3, achk = tid & 7;
    #pragma unroll 1
    for (int kr = 0; kr < 256; kr += 64) {
      short8 ra = *(const short8*)(h0bf + (size_t)(m0 + arow)*256 + kr + achk*8);
      short8 rb[4];
      #pragma unroll
      for (int p = 0; p < 4; ++p) {
        int idx = p*512 + tid;
        rb[p] = *(const short8*)(wi2b + (size_t)(idx >> 3)*256 + kr + (idx & 7)*8);
      }
      if (kr) __syncthreads();
      *(short8*)&As[arow][achk*8] = ra;
      #pragma unroll
      for (int p = 0; p < 4; ++p) {
        int idx = p*512 + tid;
        *(short8*)&Bs[idx >> 3][(idx & 7)*8] = rb[p];
      }
      __syncthreads();
      #pragma unroll
      for (int cc = 0; cc < 2; ++cc) {
        short8 bfr[2];
        #pragma unroll
        for (int t = 0; t < 2; ++t)
          bfr[t] = *(const short8*)&Bs[n0 + t*16 + col][cc*32 + quad*8];
        #pragma unroll
        for (int ms = 0; ms < 4; ++ms) {
          short8 afr = *(const short8*)&As[ms*16 + col][cc*32 + quad*8];
          acc[ms][0] = __builtin_amdgcn_mfma_f32_16x16x32_bf16(afr, bfr[0], acc[ms][0], 0, 0, 0);
          acc[ms][1] = __builtin_amdgcn_mfma_f32_16x16x32_bf16(afr, bfr[1], acc[ms][1], 0, 0, 0);
        }
      }
    }
    #pragma unroll
    for (int ms = 0; ms < 4; ++ms)
      #pragma unroll
      for (int t = 0; t < 2; ++t)
        #pragma unroll
        for (int r = 0; r < 4; ++r)
          h2out[(size_t)(m0 + ms*16 + quad*4 + r)*256 + n0 + t*16 + col] = acc[ms][t][r];
    return;
  }

  if (blockIdx.x >= 32) {
    // ---- lin1 arm ----
    short (*Ab)[512][8] = (short (*)[512][8])pool;
    short (*Bb)[512][8] = (short (*)[512][8])(pool + 8192);
    int sub = tid >> 8, stid = tid & 255;
    int lane = stid & 63, w = stid >> 6;
    int quad = lane >> 4, col = lane & 15;
    int idx = (blockIdx.x - 32)*2 + sub;   // [0,256)
    int mt = idx & 7, ntb = (idx >> 3) & 3, kz = idx >> 5;
    int c0 = (kz <= 2) ? kz*22 : 44 + (kz - 2)*20;
    int cn = (kz < 2) ? 22 : ((kz == 7) ? 18 : 20);
    int Nr = cn >> 1;
    int m0 = mt*64;
    floatx4 acc[4];
    #pragma unroll
    for (int t = 0; t < 4; ++t) {
      float bv = (kz == 0) ? b_lin1[ntb*64 + t*16 + col] : 0.f;
      #pragma unroll
      for (int r = 0; r < 4; ++r) acc[t][r] = bv;
    }
    const short* asrc = p3bf + (size_t)(m0 + w*16 + col)*5184 + c0*32 + quad*8;
    const short* bsrc = wl1p + ((size_t)((ntb*4 + w)*162 + c0)*64 + lane)*8;
    short8 ra0 = *(const short8*)asrc;
    short8 ra1 = *(const short8*)(asrc + 32);
    short8 rb0 = *(const short8*)bsrc;
    short8 rb1 = *(const short8*)(bsrc + 512);
    asrc += 64; bsrc += 1024;
    #pragma unroll 1
    for (int r = 0; r < Nr; ++r) {
      *(short8*)&Ab[0][tid][0] = ra0;
      *(short8*)&Ab[1][tid][0] = ra1;
      *(short8*)&Bb[0][tid][0] = rb0;
      *(short8*)&Bb[1][tid][0] = rb1;
      if (r + 1 < Nr) {
        ra0 = *(const short8*)asrc;
        ra1 = *(const short8*)(asrc + 32);
        rb0 = *(const short8*)bsrc;
        rb1 = *(const short8*)(bsrc + 512);
        asrc += 64; bsrc += 1024;
      }
      __syncthreads();
      #pragma unroll
      for (int cc = 0; cc < 2; ++cc) {
        short8 a = *(const short8*)&Ab[cc][sub*256 + w*64 + lane][0];
        #pragma unroll
        for (int t = 0; t < 4; ++t) {
          short8 b = *(const short8*)&Bb[cc][sub*256 + t*64 + lane][0];
          acc[t] = __builtin_amdgcn_mfma_f32_16x16x32_bf16(a, b, acc[t], 0, 0, 0);
        }
      }
      __syncthreads();
    }
    float* to = t1 + (size_t)kz * 131072;
    #pragma unroll
    for (int t = 0; t < 4; ++t)
      #pragma unroll
      for (int r = 0; r < 4; ++r)
        to[(size_t)(m0 + w*16 + quad*4 + r)*256 + ntb*64 + t*16 + col] = acc[t][r];
    return;
  }

  // ---- t_h arm ----
  short (*hbuf)[16][264] = (short (*)[16][264])pool;
  int lane = tid & 63, wid = tid >> 6;
  int quad = lane >> 4, col = lane & 15;
  int bb = blockIdx.x * 16;
  int n0 = wid * 32;
  short8 w1f[2][8];
  #pragma unroll
  for (int t = 0; t < 2; ++t)
    #pragma unroll
    for (int c = 0; c < 8; ++c)
      w1f[t][c] = *(const short8*)(whh1b + (n0 + t*16 + col)*256 + c*32 + quad*8);
  floatx4 ihcr[2];
  #pragma unroll
  for (int t = 0; t < 2; ++t) {
    float4 iv = *(const float4*)(ihc + (size_t)(bb + col)*256 + n0 + t*16 + quad*4);
    ihcr[t][0] = iv.x; ihcr[t][1] = iv.y; ihcr[t][2] = iv.z; ihcr[t][3] = iv.w;
  }
  #pragma unroll
  for (int t = 0; t < 2; ++t)
    #pragma unroll
    for (int c = 0; c < 8; ++c) asm volatile("" : "+v"(w1f[t][c]));

  {
    int m = tid >> 5, c = tid & 31;
    *(short8*)&hbuf[0][m][c*8] = *(const short8*)(h0bf + (size_t)(bb + m)*256 + c*8);
  }
  __syncthreads();
  #pragma unroll 1
  for (int i = 0; i < 23; ++i) {
    int cur = i & 1;
    floatx4 a1[2];
    #pragma unroll
    for (int t = 0; t < 2; ++t) {
      a1[t][0] = ihcr[t][0]; a1[t][1] = ihcr[t][1];
      a1[t][2] = ihcr[t][2]; a1[t][3] = ihcr[t][3];
    }
    #pragma unroll
    for (int c = 0; c < 8; ++c) {
      short8 hb = *(const short8*)&hbuf[cur][col][c*32 + quad*8];
      a1[0] = __builtin_amdgcn_mfma_f32_16x16x32_bf16(w1f[0][c], hb, a1[0], 0, 0, 0);
      a1[1] = __builtin_amdgcn_mfma_f32_16x16x32_bf16(w1f[1][c], hb, a1[1], 0, 0, 0);
    }
    #pragma unroll
    for (int t = 0; t < 2; ++t) {
      short4_t pk;
      #pragma unroll
      for (int r = 0; r < 4; ++r) pk[r] = f2bf(fast_tanh(a1[t][r]));
      *(short4_t*)&hbuf[cur ^ 1][col][n0 + t*16 + quad*4] = pk;
      *(short4_t*)(hseq + ((size_t)i*512 + bb + col)*256 + n0 + t*16 + quad*4) = pk;
    }
    __syncthreads();
  }
}

// ---------------- fusedB: blocks 0-31 lin_fin, blocks 32-215 y_gemm ------------
__global__ __launch_bounds__(512) void fusedB(
    const short* __restrict__ hseq, const short* __restrict__ wih2b,
    const float* __restrict__ bih2, const float* __restrict__ bhh2,
    float* __restrict__ yseq,
    const float* __restrict__ t1, const float* __restrict__ w_lin2,
    const float* __restrict__ b_lin2, float* __restrict__ outc) {
  __shared__ __align__(16) short As[64][72];
  __shared__ __align__(16) short Bs[256][72];
  __shared__ float st[16][257];
  int tid = threadIdx.x;

  if (blockIdx.x < 32) {
    // ---- lin_fin arm (512 threads) ----
    int bb = blockIdx.x * 16;
    for (int i = tid; i < 4096; i += 512) {
      int m = i >> 8, k = i & 255;
      size_t i0 = (size_t)(bb + m)*256 + k;
      float s = 0.f;
      #pragma unroll
      for (int z = 0; z < 8; ++z) s += t1[i0 + (size_t)z*131072];
      st[m][k] = fast_tanh(s);
    }
    __syncthreads();
    if (tid < 192) {
      int r = tid / 12, j = tid % 12;
      float s = b_lin2[j];
      #pragma unroll 1
      for (int k = 0; k < 256; ++k) s += st[r][k] * w_lin2[j*256 + k];
      outc[(size_t)(bb + r)*12 + j] = s;
    }
    return;
  }

  // ---- y_gemm arm ----
  int lane = tid & 63, w = tid >> 6;
  int quad = lane >> 4, col = lane & 15;
  int m0 = (blockIdx.x - 32) * 64;
  int n0 = w * 32;
  float bv[2];
  #pragma unroll
  for (int t = 0; t < 2; ++t) {
    int n = n0 + t*16 + col;
    bv[t] = bih2[n] + bhh2[n];
  }
  floatx4 acc[4][2];
  #pragma unroll
  for (int ms = 0; ms < 4; ++ms)
    #pragma unroll
    for (int t = 0; t < 2; ++t)
      #pragma unroll
      for (int r = 0; r < 4; ++r) acc[ms][t][r] = bv[t];
  int arow = tid >> 3, achk = tid & 7;
  #pragma unroll 1
  for (int kr = 0; kr < 256; kr += 64) {
    short8 ra = *(const short8*)(hseq + (size_t)(m0 + arow)*256 + kr + achk*8);
    short8 rb[4];
    #pragma unroll
    for (int p = 0; p < 4; ++p) {
      int idx = p*512 + tid;
      rb[p] = *(const short8*)(wih2b + (size_t)(idx >> 3)*256 + kr + (idx & 7)*8);
    }
    if (kr) __syncthreads();
    *(short8*)&As[arow][achk*8] = ra;
    #pragma unroll
    for (int p = 0; p < 4; ++p) {
      int idx = p*512 + tid;
      *(short8*)&Bs[idx >> 3][(idx & 7)*8] = rb[p];
    }
    __syncthreads();
    #pragma unroll
    for (int cc = 0; cc < 2; ++cc) {
      short8 bfr[2];
      #pragma unroll
      for (int t = 0; t < 2; ++t)
        bfr[t] = *(const short8*)&Bs[n0 + t*16 + col][cc*32 + quad*8];
      #pragma unroll
      for (int ms = 0; ms < 4; ++ms) {
        short8 afr = *(const short8*)&As[ms*16 + col][cc*32 + quad*8];
        acc[ms][0] = __builtin_amdgcn_mfma_f32_16x16x32_bf16(afr, bfr[0], acc[ms][0], 0, 0, 0);
        acc[ms][1] = __builtin_amdgcn_mfma_f32_16x16x32_bf16(afr, bfr[1], acc[ms][1], 0, 0, 0);
      }
    }
  }
  #pragma unroll
  for (int ms = 0; ms < 4; ++ms)
    #pragma unroll
    for (int t = 0; t < 2; ++t)
      #pragma unroll
      for (int r = 0; r < 4; ++r)
        yseq[(size_t)(m0 + ms*16 + quad*4 + r)*256 + n0 + t*16 + col] = acc[ms][t][r];
}

// ---------------- t_h2: serial h2-recurrence, whh2 ONLY + precomputed y ---------
__global__ __launch_bounds__(512) void t_h2(
    const float* __restrict__ h2in, const float* __restrict__ yseq,
    const short* __restrict__ whh2b,
    const float* __restrict__ w_fc, const float* __restrict__ b_fc,
    float* __restrict__ preds) {
  __shared__ __align__(16) short h2buf[2][16][264];
  __shared__ float predsAll[23][8][16];
  int tid = threadIdx.x;
  int lane = tid & 63, wid = tid >> 6;
  int quad = lane >> 4, col = lane & 15;
  int bb = blockIdx.x * 16;
  int n0 = wid * 32;
  short8 w3f[2][8];
  #pragma unroll
  for (int t = 0; t < 2; ++t)
    #pragma unroll
    for (int c = 0; c < 8; ++c)
      w3f[t][c] = *(const short8*)(whh2b + (n0 + t*16 + col)*256 + c*32 + quad*8);
  float4 wfcv[2];
  #pragma unroll
  for (int t = 0; t < 2; ++t)
    wfcv[t] = *(const float4*)(w_fc + n0 + t*16 + quad*4);
  float bfc = b_fc[0];
  #pragma unroll
  for (int t = 0; t < 2; ++t)
    #pragma unroll
    for (int c = 0; c < 8; ++c) asm volatile("" : "+v"(w3f[t][c]));

  for (int i = tid; i < 4096; i += 512) {
    int m = i >> 8, k = i & 255;
    h2buf[0][m][k] = f2bf(h2in[(size_t)(bb + m)*256 + k]);
  }
  __syncthreads();
  #pragma unroll 1
  for (int i = 0; i < 23; ++i) {
    int cur = i & 1;
    float4 yv[2];
    #pragma unroll
    for (int t = 0; t < 2; ++t)
      yv[t] = *(const float4*)(yseq + ((size_t)i*512 + bb + col)*256 + n0 + t*16 + quad*4);
    floatx4 z0 = {0.f,0.f,0.f,0.f}, z1 = {0.f,0.f,0.f,0.f};
    #pragma unroll
    for (int c = 0; c < 8; ++c) {
      short8 gb = *(const short8*)&h2buf[cur][col][c*32 + quad*8];
      z0 = __builtin_amdgcn_mfma_f32_16x16x32_bf16(w3f[0][c], gb, z0, 0, 0, 0);
      z1 = __builtin_amdgcn_mfma_f32_16x16x32_bf16(w3f[1][c], gb, z1, 0, 0, 0);
    }
    float pr = 0.f;
    short4_t o0, o1;
    const float* y0p = (const float*)&yv[0];
    const float* y1p = (const float*)&yv[1];
    const float* wf0 = (const float*)&wfcv[0];
    const float* wf1 = (const float*)&wfcv[1];
    #pragma unroll
    for (int r = 0; r < 4; ++r) {
      float t0 = fast_tanh(z0[r] + y0p[r]);
      float t1 = fast_tanh(z1[r] + y1p[r]);
      o0[r] = f2bf(t0); o1[r] = f2bf(t1);
      pr += t0*wf0[r] + t1*wf1[r];
    }
    *(short4_t*)&h2buf[cur ^ 1][col][n0 + quad*4] = o0;
    *(short4_t*)&h2buf[cur ^ 1][col][n0 + 16 + quad*4] = o1;
    pr += __shfl_xor(pr, 16, 64);
    pr += __shfl_xor(pr, 32, 64);
    if (lane < 16) predsAll[i][wid][lane] = pr;
    __syncthreads();
  }
  if (tid < 16) {
    #pragma unroll 1
    for (int p = 0; p < 23; ++p) {
      float sv = bfc;
      #pragma unroll
      for (int w = 0; w < 8; ++w) sv += predsAll[p][w][tid];
      preds[(size_t)(bb + tid)*23 + p] = sv;
    }
  }
}

// ---------------- launch ----------------
extern "C" void kernel_launch(void* const* d_in, const int* in_sizes, int n_in,
                              void* d_out, int out_size, void* d_ws, size_t ws_size,
                              hipStream_t stream) {
  const float* x         = (const float*)d_in[0];
  const float* w1        = (const float*)d_in[1];
  const float* b1        = (const float*)d_in[2];
  const float* w2        = (const float*)d_in[3];
  const float* b2        = (const float*)d_in[4];
  const float* w3        = (const float*)d_in[5];
  const float* b3        = (const float*)d_in[6];
  const float* wih1      = (const float*)d_in[7];
  const float* whh1      = (const float*)d_in[8];
  const float* bih1      = (const float*)d_in[9];
  const float* bhh1      = (const float*)d_in[10];
  const float* wih2      = (const float*)d_in[11];
  const float* whh2      = (const float*)d_in[12];
  const float* bih2      = (const float*)d_in[13];
  const float* bhh2      = (const float*)d_in[14];
  const float* w_init_h  = (const float*)d_in[15];
  const float* b_init_h  = (const float*)d_in[16];
  const float* w_init_h2 = (const float*)d_in[17];
  const float* b_init_h2 = (const float*)d_in[18];
  const float* w_fc      = (const float*)d_in[19];
  const float* b_fc      = (const float*)d_in[20];
  const float* w_lin1    = (const float*)d_in[21];
  const float* b_lin1    = (const float*)d_in[22];
  const float* w_lin2    = (const float*)d_in[23];
  const float* b_lin2    = (const float*)d_in[24];
  float* ws  = (float*)d_ws;
  float* out = (float*)d_out;

  prep_kernel<<<1438, 256, 0, stream>>>(w1, w2, w3, w_init_h, wih1, w_init_h2,
                                        whh1, wih2, whh2, ws);
  conv1_mfma<<<2696, 256, 0, stream>>>(x, (const short*)(ws + OFF_B1P), b1,
                                       (short*)(ws + OFF_P1),
                                       w_lin1, (short*)(ws + OFF_WL1P));
  conv2_mfma<<<1024, 256, 0, stream>>>((const short*)(ws + OFF_P1),
                                       (const short*)(ws + OFF_B2P), b2,
                                       (short*)(ws + OFF_P2));
  conv3_mfma<<<512, 256, 0, stream>>>((const short*)(ws + OFF_P2),
                                      (const short*)(ws + OFF_B3P), b3,
                                      (short*)(ws + OFF_P3BF), ws + OFF_ME);
  init_kernel<<<256, 256, 0, stream>>>(ws + OFF_ME, ws + OFF_WIHT, b_init_h,
                                       ws + OFF_WIH1T, bih1, bhh1,
                                       (short*)(ws + OFF_H0BF), ws + OFF_IHC);
  fusedA<<<168, 512, 0, stream>>>((const short*)(ws + OFF_H0BF), ws + OFF_IHC,
                                  (const short*)(ws + OFF_WHH1B),
                                  (short*)(ws + OFF_HSEQ),
                                  (const short*)(ws + OFF_P3BF),
                                  (const short*)(ws + OFF_WL1P),
                                  b_lin1, ws + OFF_T1,
                                  (const short*)(ws + OFF_WI2B), b_init_h2,
                                  ws + OFF_H2);
  fusedB<<<216, 512, 0, stream>>>((const short*)(ws + OFF_HSEQ),
                                  (const short*)(ws + OFF_WIH2B),
                                  bih2, bhh2, ws + OFF_Y,
                                  ws + OFF_T1, w_lin2, b_lin2, out + 11776);
  t_h2<<<32, 512, 0, stream>>>(ws + OFF_H2, ws + OFF_Y,
                               (const short*)(ws + OFF_WHH2B),
                               w_fc, b_fc, out);
}

// Round 10
// 282.802 us; speedup vs baseline: 1.0342x; 1.0342x over previous
//
#include <hip/hip_runtime.h>
#include <hip/hip_bf16.h>

typedef __attribute__((ext_vector_type(8))) short short8;
typedef __attribute__((ext_vector_type(4))) short short4_t;
typedef __attribute__((ext_vector_type(4))) float floatx4;

// ---------------- workspace layout (float offsets) ----------------
#define OFF_B1P   0        // conv1 B frags [7][64][8] bf16
#define OFF_B2P   1792     // conv2 B frags [2][14][64][8] bf16
#define OFF_B3P   8960     // conv3 B frags [4][27][64][8] bf16
#define OFF_WIHT  36608    // w_init_h^T  (64,256)
#define OFF_WIH1T 52992    // wih1^T      (64,256)
#define OFF_WI2B  69376    // w_init_h2 bf16 row-major [t][k] (reuses old wi2t slot)
#define OFF_WHH1B 134912   // whh1 bf16 row-major [t][k]
#define OFF_WIH2B 167680   // wih2 bf16 row-major
#define OFF_WHH2B 200448   // whh2 bf16 row-major
#define OFF_WL1P  233216   // w_lin1 MFMA frags [nt16][c162][lane64][j8] bf16
#define OFF_ME    896768   // mean_enc (512,64)
#define OFF_H0BF  929536   // h0 bf16 [512][256] (reuses old fp32 h slot)
#define OFF_H2    1060608  // h2_0(512,256) fp32
#define OFF_IHC   1191680  // ih_const (512,256)
#define OFF_P1    1322752  // p1 bf16 [512][1296][16]
#define OFF_T1    1322752  // lin1 partials 8x(512,256) fp32 (over dead p1)
#define OFF_Y     2377728  // y = Hseq@wih2^T + b2, f32 [23*512][256] (over dead p1)
#define OFF_HSEQ  5392384  // h_1..h_23 bf16 [23*512][256] (over dead p1/p2)
#define OFF_P2    6631168  // p2 bf16 [512][324][32]
#define OFF_P3BF  9285376  // p3 bf16 [512][5184]

#define S2_H 88
#define S2_D 1760
#define S3_H 88
#define S3_D 1760
#define S3_HALF 14080

static __device__ inline short f2bf(float f) {
  union { __hip_bfloat16 h; short s; } u;
  u.h = __float2bfloat16(f);
  return u.s;
}
static __device__ inline float bf2f(short s) {
  union { unsigned u; float f; } v;
  v.u = ((unsigned)(unsigned short)s) << 16;
  return v.f;
}
// 5-instr tanh: 1 - 2/(e^{2x}+1); inf-safe both directions
static __device__ inline float fast_tanh(float x) {
  float e = __expf(2.f * x);
  return __builtin_fmaf(-2.f, __builtin_amdgcn_rcpf(e + 1.f), 1.f);
}

// ---------------- prep: weight frag packs + RNN packs ----------------
__global__ __launch_bounds__(256) void prep_kernel(
    const float* __restrict__ w1, const float* __restrict__ w2, const float* __restrict__ w3,
    const float* __restrict__ w_init_h, const float* __restrict__ wih1,
    const float* __restrict__ w_init_h2, const float* __restrict__ whh1,
    const float* __restrict__ wih2, const float* __restrict__ whh2,
    float* __restrict__ ws) {
  int i = blockIdx.x * 256 + threadIdx.x;
  if (i < 3584) {
    int j = i & 7, l = (i >> 3) & 63, c = i >> 9;
    int k = c*32 + ((l >> 4) << 3) + j;
    int tap = k >> 3, icp = k & 7, oc = l & 15;
    float v = (tap < 27 && icp < 6) ? w1[(oc*6 + icp)*27 + tap] : 0.f;
    ((__hip_bfloat16*)(ws + OFF_B1P))[i] = __float2bfloat16(v);
    return;
  }
  i -= 3584;
  if (i < 14336) {
    int j = i & 7, l = (i >> 3) & 63, cc = i >> 9;
    int c = cc % 14, nt = cc / 14;
    int k = c*32 + ((l >> 4) << 3) + j;
    int tap = k >> 4, ic = k & 15, oc = nt*16 + (l & 15);
    float v = (tap < 27) ? w2[(oc*16 + ic)*27 + tap] : 0.f;
    ((__hip_bfloat16*)(ws + OFF_B2P))[i] = __float2bfloat16(v);
    return;
  }
  i -= 14336;
  if (i < 55296) {
    int j = i & 7, l = (i >> 3) & 63, cc = i >> 9;
    int c = cc % 27, nt = cc / 27;
    int k = c*32 + ((l >> 4) << 3) + j;
    int ic = k & 31, oc = nt*16 + (l & 15);
    ((__hip_bfloat16*)(ws + OFF_B3P))[i] = __float2bfloat16(w3[(oc*32 + ic)*27 + c]);
    return;
  }
  i -= 55296;
  if (i < 16384) { int t = i & 255, k = i >> 8; ws[OFF_WIHT + i]  = w_init_h[t*64 + k];  return; }
  i -= 16384;
  if (i < 16384) { int t = i & 255, k = i >> 8; ws[OFF_WIH1T + i] = wih1[t*64 + k];      return; }
  i -= 16384;
  if (i < 65536) { ((__hip_bfloat16*)(ws + OFF_WI2B))[i] = __float2bfloat16(w_init_h2[i]); return; }
  i -= 65536;
  if (i < 65536) { ((__hip_bfloat16*)(ws + OFF_WHH1B))[i] = __float2bfloat16(whh1[i]); return; }
  i -= 65536;
  if (i < 65536) { ((__hip_bfloat16*)(ws + OFF_WIH2B))[i] = __float2bfloat16(wih2[i]); return; }
  i -= 65536;
  if (i < 65536) { ((__hip_bfloat16*)(ws + OFF_WHH2B))[i] = __float2bfloat16(whh2[i]); return; }
}

// ---------------- conv1 MFMA + w_lin1 pack tail blocks ----------------
// R9 post-mortem: XOR swizzle REVERTED (conflicts 5.3M->6.8M, VALU 34->50%,
// slightly slower — the read-interference model was wrong). Real limiter:
// 47.6KB slab -> only 3 blocks/CU (26% occupancy), too few waves to hide
// LDS + staging latency. R10: split each block's H-range in half (hh), slab
// 8 dslots x 38 h x 5 w = 24.3KB -> 6 blocks/CU (~75% wave cap). Grid 2048->
// 4096 compute blocks; h-halo overfetch +2.7%. Pack arm stays vectorized.
__global__ __launch_bounds__(256) void conv1_mfma(
    const float* __restrict__ x, const short* __restrict__ b1p,
    const float* __restrict__ bias, short* __restrict__ p1,
    const float* __restrict__ w_lin1, short* __restrict__ wl1p) {
  __shared__ __align__(16) short slab[8 * 38 * 5 * 8];   // 12160 shorts, 24.3KB
  int tid = threadIdx.x;
  if (blockIdx.x >= 4096) {
    int u = (blockIdx.x - 4096)*256 + tid;   // [0, 165888)
    int l = u & 63, cc = u >> 6;
    int c = cc % 162, nt = cc / 162;
    int n = nt*16 + (l & 15);
    int k0 = c*32 + ((l >> 4) << 3);
    const float* src = w_lin1 + (size_t)n*5184 + k0;
    float4 v0 = *(const float4*)src;
    float4 v1 = *(const float4*)(src + 4);
    short8 s;
    s[0] = f2bf(v0.x); s[1] = f2bf(v0.y); s[2] = f2bf(v0.z); s[3] = f2bf(v0.w);
    s[4] = f2bf(v1.x); s[5] = f2bf(v1.y); s[6] = f2bf(v1.z); s[7] = f2bf(v1.w);
    *(short8*)(wl1p + (size_t)u*8) = s;
    return;
  }
  int bq = blockIdx.x >> 1, hh = blockIdx.x & 1;
  int b = bq >> 2, q = bq & 3;
  short8 z8 = {0,0,0,0,0,0,0,0};
  for (int i = tid; i < 1520; i += 256) *(short8*)(slab + i*8) = z8;
  __syncthreads();
  {
    // one staging unit per thread: 8 dslots x 28 float4-groups
    int dslot = tid >> 5, gi = tid & 31;
    if (gi < 28) {
      int g = gi + (hh ? 26 : 0);              // aligned group range per half
      int d = 6*q - 1 + dslot;
      if ((unsigned)d < 24u) {
        float4 v[6];
        #pragma unroll
        for (int ic = 0; ic < 6; ++ic)
          v[ic] = *(const float4*)(x + ((size_t)(b*6 + ic)*24 + d)*216 + g*4);
        const float* vv = (const float*)v;
        int hbase = 36*hh - 1;                 // slab row r = h - hbase
        #pragma unroll
        for (int e = 0; e < 4; ++e) {
          int p = g*4 + e;
          int h = p/3, w = p - h*3;
          int r = h - hbase;
          if ((unsigned)r < 38u) {
            short8 s = z8;
            #pragma unroll
            for (int ic = 0; ic < 6; ++ic) s[ic] = f2bf(vv[ic*4 + e]);
            *(short8*)(slab + (dslot*190 + r*5 + 1 + w)*8) = s;
          }
        }
      }
    }
  }
  int lane = tid & 63, wid = tid >> 6;
  int quad = lane >> 4, col = lane & 15;
  short8 bf[7];
  #pragma unroll
  for (int c = 0; c < 7; ++c) bf[c] = *(const short8*)(b1p + (c*64 + lane)*8);
  int tapslot[7];
  #pragma unroll
  for (int c = 0; c < 7; ++c) {
    int tap = c*4 + quad;
    int tt = tap < 27 ? tap : 26;
    int kd = tt/9, rr = tt - kd*9, kh = rr/3, kw = rr - kh*3;
    tapslot[c] = kd*190 + kh*5 + kw;
  }
  float bv = bias[col];
  __syncthreads();
  for (int tile = wid; tile < 41; tile += 4) {
    int m = tile*16 + col; if (m > 647) m = 647;
    int dd = m & 1, dh = (m >> 1) & 1;
    int P = m >> 2;
    int t2 = P/3; int w = P - t2*3;
    int pdl = t2/18; int ph = t2 - pdl*18;
    int sbase = (2*pdl + dd)*190 + (2*ph + dh)*5 + w;
    floatx4 acc = {0.f, 0.f, 0.f, 0.f};
    #pragma unroll
    for (int c = 0; c < 7; ++c) {
      short8 af = *(const short8*)(slab + (sbase + tapslot[c])*8);
      acc = __builtin_amdgcn_mfma_f32_16x16x32_bf16(af, bf[c], acc, 0, 0, 0);
    }
    float v = fmaxf(fmaxf(acc[0], acc[1]), fmaxf(acc[2], acc[3]));
    v = fmaxf(v + bv, 0.f);
    int Pl = tile*4 + quad;
    if (Pl < 162) {
      int t2o = Pl/3; int wo = Pl - t2o*3;
      int pdo = t2o/18; int pho = t2o - pdo*18;
      int Pout = q*324 + hh*54 + pdo*108 + pho*3 + wo;
      p1[((size_t)b*1296 + Pout)*16 + col] = f2bf(v);
    }
  }
}

// ---------------- conv2 MFMA, halo slab: p1 -> p2 bf16 [b][324][32] ----------------
__global__ __launch_bounds__(256) void conv2_mfma(
    const short* __restrict__ p1, const short* __restrict__ b2p,
    const float* __restrict__ bias2, short* __restrict__ p2g) {
  __shared__ __align__(16) short slab[14 * S2_D];
  int tid = threadIdx.x;
  int b = blockIdx.x >> 1, qh = blockIdx.x & 1;
  short8 z8 = {0,0,0,0,0,0,0,0};
  for (int i = tid; i < 3080; i += 256) *(short8*)(slab + i*8) = z8;
  __syncthreads();
  for (int i = tid; i < 1440; i += 256) {
    int c8 = i % 6; int r = i / 6; int hr = r % 20; int d = r / 20;
    int hg = 18*qh - 1 + hr;
    if ((unsigned)hg < 36u) {
      short8 v = *(const short8*)(p1 + ((size_t)b*1296 + (d*36 + hg)*3)*16 + c8*8);
      *(short8*)(slab + (d+1)*S2_D + hr*S2_H + 16 + c8*8) = v;
    }
  }
  int lane = tid & 63, wid = tid >> 6;
  int quad = lane >> 4, col = lane & 15;
  short8 bf[2][14];
  #pragma unroll
  for (int nt = 0; nt < 2; ++nt)
    #pragma unroll
    for (int c = 0; c < 14; ++c)
      bf[nt][c] = *(const short8*)(b2p + ((nt*14 + c)*64 + lane)*8);
  int tq = quad >> 1, icoff = (quad & 1) * 8;
  int tapoff[14];
  #pragma unroll
  for (int c = 0; c < 14; ++c) {
    int tap = 2*c + tq; if (tap > 26) tap = 26;
    int kd = tap/9, rr = tap - kd*9, kh = rr/3, kw = rr - kh*3;
    tapoff[c] = kd*S2_D + kh*S2_H + kw*16 + icoff;
  }
  float bv0 = bias2[col], bv1 = bias2[16 + col];
  __syncthreads();
  for (int tile = wid; tile < 41; tile += 4) {
    int m = tile*16 + col; if (m > 647) m = 647;
    int dd = m & 1, dh = (m >> 1) & 1;
    int P = m >> 2;
    int t = P/3; int w = P - t*3;
    int pd = t/9; int phl = t - pd*9;
    int base = (2*pd + dd)*S2_D + (2*phl + dh)*S2_H + w*16;
    floatx4 a0 = {0.f,0.f,0.f,0.f}, a1 = {0.f,0.f,0.f,0.f};
    #pragma unroll
    for (int c = 0; c < 14; ++c) {
      short8 a = *(const short8*)(slab + base + tapoff[c]);
      a0 = __builtin_amdgcn_mfma_f32_16x16x32_bf16(a, bf[0][c], a0, 0, 0, 0);
      a1 = __builtin_amdgcn_mfma_f32_16x16x32_bf16(a, bf[1][c], a1, 0, 0, 0);
    }
    int P2l = tile*4 + quad;
    if (P2l < 162) {
      float v0 = fmaxf(fmaxf(fmaxf(a0[0],a0[1]), fmaxf(a0[2],a0[3])) + bv0, 0.f);
      float v1 = fmaxf(fmaxf(fmaxf(a1[0],a1[1]), fmaxf(a1[2],a1[3])) + bv1, 0.f);
      int t2 = P2l/3; int w2 = P2l - t2*3;
      int pd2 = t2/9; int ph2 = t2 - pd2*9;
      size_t off = ((size_t)b*324 + (pd2*18 + 9*qh + ph2)*3 + w2)*32;
      p2g[off + col] = f2bf(v0);
      p2g[off + 16 + col] = f2bf(v1);
    }
  }
}

// ---------------- conv3 MFMA, dual ic-half halo slabs: p2 -> p3bf + mean ----------------
__global__ __launch_bounds__(256) void conv3_mfma(
    const short* __restrict__ p2g, const short* __restrict__ b3p,
    const float* __restrict__ bias3,
    short* __restrict__ p3bf, float* __restrict__ me) {
  __shared__ __align__(16) short slab[2 * S3_HALF];
  __shared__ float smean[4][32];
  int tid = threadIdx.x;
  int b = blockIdx.x;
  short8 z8 = {0,0,0,0,0,0,0,0};
  for (int i = tid; i < 3520; i += 256) *(short8*)(slab + i*8) = z8;
  __syncthreads();
  for (int i = tid; i < 1296; i += 256) {
    int c8 = i & 1;
    int hv = (i >> 1) & 1;
    int cell = i >> 2;
    int t = cell/3; int w = cell - t*3;
    int d = t/18; int h = t - d*18;
    short8 v = *(const short8*)(p2g + ((size_t)b*324 + cell)*32 + hv*16 + c8*8);
    *(short8*)(slab + hv*S3_HALF + (d+1)*S3_D + (h+1)*S3_H + (w+1)*16 + c8*8) = v;
  }
  int lane = tid & 63, wid = tid >> 6;
  int quad = lane >> 4, col = lane & 15;
  int ntp = (wid & 1) * 2;
  int tsel = wid >> 1;
  short8 bf[2][27];
  #pragma unroll
  for (int u = 0; u < 2; ++u)
    #pragma unroll
    for (int c = 0; c < 27; ++c)
      bf[u][c] = *(const short8*)(b3p + (((ntp+u)*27 + c)*64 + lane)*8);
  const short* sb = slab + (quad >> 1)*S3_HALF + (quad & 1)*8;
  float bva = bias3[ntp*16 + col], bvb = bias3[(ntp+1)*16 + col];
  float ms0 = 0.f, ms1 = 0.f;
  __syncthreads();
  for (int tile = tsel; tile < 21; tile += 2) {
    int m = tile*16 + col; if (m > 323) m = 323;
    int dd = m & 1, dh = (m >> 1) & 1;
    int P = m >> 2;
    int t = P/3; int w = P - t*3;
    int pd = t/9; int ph = t - pd*9;
    const short* ap = sb + (2*pd + dd)*S3_D + (2*ph + dh)*S3_H + w*16;
    floatx4 a0 = {0.f,0.f,0.f,0.f}, a1 = {0.f,0.f,0.f,0.f};
    #pragma unroll
    for (int c = 0; c < 27; ++c) {
      const int kd = c/9, rr = c - kd*9, kh = rr/3, kw = rr - kh*3;
      short8 a = *(const short8*)(ap + kd*S3_D + kh*S3_H + kw*16);
      a0 = __builtin_amdgcn_mfma_f32_16x16x32_bf16(a, bf[0][c], a0, 0, 0, 0);
      a1 = __builtin_amdgcn_mfma_f32_16x16x32_bf16(a, bf[1][c], a1, 0, 0, 0);
    }
    int Pout = tile*4 + quad;
    if (Pout < 81) {
      float v0 = fmaxf(fmaxf(fmaxf(a0[0],a0[1]), fmaxf(a0[2],a0[3])) + bva, 0.f);
      float v1 = fmaxf(fmaxf(fmaxf(a1[0],a1[1]), fmaxf(a1[2],a1[3])) + bvb, 0.f);
      size_t oi = ((size_t)b*81 + Pout)*64 + ntp*16 + col;
      p3bf[oi] = f2bf(v0);
      p3bf[oi + 16] = f2bf(v1);
      ms0 += v0; ms1 += v1;
    }
  }
  ms0 += __shfl_xor(ms0, 16, 64); ms0 += __shfl_xor(ms0, 32, 64);
  ms1 += __shfl_xor(ms1, 16, 64); ms1 += __shfl_xor(ms1, 32, 64);
  if (lane < 16) { smean[wid][lane] = ms0; smean[wid][16 + lane] = ms1; }
  __syncthreads();
  if (tid < 64) {
    float s = (tid < 32) ? (smean[0][tid] + smean[2][tid])
                         : (smean[1][tid-32] + smean[3][tid-32]);
    me[b*64 + tid] = s * (1.f / 81.f);
  }
}

// ---------------- init: h0 (bf16) + ihc only; K=64. 256 blocks x 2 rows -------
__global__ __launch_bounds__(256) void init_kernel(
    const float* __restrict__ me, const float* __restrict__ wiht,
    const float* __restrict__ b_init_h, const float* __restrict__ wih1t,
    const float* __restrict__ bih1, const float* __restrict__ bhh1,
    short* __restrict__ h0bf, float* __restrict__ ihcout) {
  __shared__ float sme[2][64];
  int t = threadIdx.x; int bb = blockIdx.x * 2;
  if (t < 128) sme[t >> 6][t & 63] = me[(bb + (t >> 6))*64 + (t & 63)];
  __syncthreads();
  float a0 = b_init_h[t], a1 = a0;
  float c0 = bih1[t] + bhh1[t], c1 = c0;
  #pragma unroll
  for (int k = 0; k < 64; ++k) {
    float w1v = wiht[k*256 + t], w2v = wih1t[k*256 + t];
    a0 += sme[0][k]*w1v; a1 += sme[1][k]*w1v;
    c0 += sme[0][k]*w2v; c1 += sme[1][k]*w2v;
  }
  h0bf[(size_t)bb*256 + t]     = f2bf(a0);
  h0bf[(size_t)(bb+1)*256 + t] = f2bf(a1);
  ihcout[(size_t)bb*256 + t]     = c0;
  ihcout[(size_t)(bb+1)*256 + t] = c1;
}

// ---------------- fusedA: blocks 0-31 t_h, 32-159 lin1, 160-167 h2_0 GEMM -----
__global__ __launch_bounds__(512) void fusedA(
    const short* __restrict__ h0bf, const float* __restrict__ ihc,
    const short* __restrict__ whh1b, short* __restrict__ hseq,
    const short* __restrict__ p3bf, const short* __restrict__ wl1p,
    const float* __restrict__ b_lin1, float* __restrict__ t1,
    const short* __restrict__ wi2b, const float* __restrict__ b_init_h2,
    float* __restrict__ h2out) {
  __shared__ __align__(16) short pool[23040];
  int tid = threadIdx.x;

  if (blockIdx.x >= 160) {
    // ---- h2_0 arm: 64 rows x 256 cols, K=256 ----
    short (*As)[72] = (short (*)[72])pool;              // [64][72]
    short (*Bs)[72] = (short (*)[72])(pool + 4608);     // [256][72]
    int lane = tid & 63, w = tid >> 6;
    int quad = lane >> 4, col = lane & 15;
    int m0 = (blockIdx.x - 160) * 64;
    int n0 = w * 32;
    float bv[2];
    #pragma unroll
    for (int t = 0; t < 2; ++t) bv[t] = b_init_h2[n0 + t*16 + col];
    floatx4 acc[4][2];
    #pragma unroll
    for (int ms = 0; ms < 4; ++ms)
      #pragma unroll
      for (int t = 0; t < 2; ++t)
        #pragma unroll
        for (int r = 0; r < 4; ++r) acc[ms][t][r] = bv[t];
    int arow = tid >> 3, achk = tid & 7;
    #pragma unroll 1
    for (int kr = 0; kr < 256; kr += 64) {
      short8 ra = *(const short8*)(h0bf + (size_t)(m0 + arow)*256 + kr + achk*8);
      short8 rb[4];
      #pragma unroll
      for (int p = 0; p < 4; ++p) {
        int idx = p*512 + tid;
        rb[p] = *(const short8*)(wi2b + (size_t)(idx >> 3)*256 + kr + (idx & 7)*8);
      }
      if (kr) __syncthreads();
      *(short8*)&As[arow][achk*8] = ra;
      #pragma unroll
      for (int p = 0; p < 4; ++p) {
        int idx = p*512 + tid;
        *(short8*)&Bs[idx >> 3][(idx & 7)*8] = rb[p];
      }
      __syncthreads();
      #pragma unroll
      for (int cc = 0; cc < 2; ++cc) {
        short8 bfr[2];
        #pragma unroll
        for (int t = 0; t < 2; ++t)
          bfr[t] = *(const short8*)&Bs[n0 + t*16 + col][cc*32 + quad*8];
        #pragma unroll
        for (int ms = 0; ms < 4; ++ms) {
          short8 afr = *(const short8*)&As[ms*16 + col][cc*32 + quad*8];
          acc[ms][0] = __builtin_amdgcn_mfma_f32_16x16x32_bf16(afr, bfr[0], acc[ms][0], 0, 0, 0);
          acc[ms][1] = __builtin_amdgcn_mfma_f32_16x16x32_bf16(afr, bfr[1], acc[ms][1], 0, 0, 0);
        }
      }
    }
    #pragma unroll
    for (int ms = 0; ms < 4; ++ms)
      #pragma unroll
      for (int t = 0; t < 2; ++t)
        #pragma unroll
        for (int r = 0; r < 4; ++r)
          h2out[(size_t)(m0 + ms*16 + quad*4 + r)*256 + n0 + t*16 + col] = acc[ms][t][r];
    return;
  }

  if (blockIdx.x >= 32) {
    // ---- lin1 arm ----
    short (*Ab)[512][8] = (short (*)[512][8])pool;
    short (*Bb)[512][8] = (short (*)[512][8])(pool + 8192);
    int sub = tid >> 8, stid = tid & 255;
    int lane = stid & 63, w = stid >> 6;
    int quad = lane >> 4, col = lane & 15;
    int idx = (blockIdx.x - 32)*2 + sub;   // [0,256)
    int mt = idx & 7, ntb = (idx >> 3) & 3, kz = idx >> 5;
    int c0 = (kz <= 2) ? kz*22 : 44 + (kz - 2)*20;
    int cn = (kz < 2) ? 22 : ((kz == 7) ? 18 : 20);
    int Nr = cn >> 1;
    int m0 = mt*64;
    floatx4 acc[4];
    #pragma unroll
    for (int t = 0; t < 4; ++t) {
      float bv = (kz == 0) ? b_lin1[ntb*64 + t*16 + col] : 0.f;
      #pragma unroll
      for (int r = 0; r < 4; ++r) acc[t][r] = bv;
    }
    const short* asrc = p3bf + (size_t)(m0 + w*16 + col)*5184 + c0*32 + quad*8;
    const short* bsrc = wl1p + ((size_t)((ntb*4 + w)*162 + c0)*64 + lane)*8;
    short8 ra0 = *(const short8*)asrc;
    short8 ra1 = *(const short8*)(asrc + 32);
    short8 rb0 = *(const short8*)bsrc;
    short8 rb1 = *(const short8*)(bsrc + 512);
    asrc += 64; bsrc += 1024;
    #pragma unroll 1
    for (int r = 0; r < Nr; ++r) {
      *(short8*)&Ab[0][tid][0] = ra0;
      *(short8*)&Ab[1][tid][0] = ra1;
      *(short8*)&Bb[0][tid][0] = rb0;
      *(short8*)&Bb[1][tid][0] = rb1;
      if (r + 1 < Nr) {
        ra0 = *(const short8*)asrc;
        ra1 = *(const short8*)(asrc + 32);
        rb0 = *(const short8*)bsrc;
        rb1 = *(const short8*)(bsrc + 512);
        asrc += 64; bsrc += 1024;
      }
      __syncthreads();
      #pragma unroll
      for (int cc = 0; cc < 2; ++cc) {
        short8 a = *(const short8*)&Ab[cc][sub*256 + w*64 + lane][0];
        #pragma unroll
        for (int t = 0; t < 4; ++t) {
          short8 b = *(const short8*)&Bb[cc][sub*256 + t*64 + lane][0];
          acc[t] = __builtin_amdgcn_mfma_f32_16x16x32_bf16(a, b, acc[t], 0, 0, 0);
        }
      }
      __syncthreads();
    }
    float* to = t1 + (size_t)kz * 131072;
    #pragma unroll
    for (int t = 0; t < 4; ++t)
      #pragma unroll
      for (int r = 0; r < 4; ++r)
        to[(size_t)(m0 + w*16 + quad*4 + r)*256 + ntb*64 + t*16 + col] = acc[t][r];
    return;
  }

  // ---- t_h arm ----
  short (*hbuf)[16][264] = (short (*)[16][264])pool;
  int lane = tid & 63, wid = tid >> 6;
  int quad = lane >> 4, col = lane & 15;
  int bb = blockIdx.x * 16;
  int n0 = wid * 32;
  short8 w1f[2][8];
  #pragma unroll
  for (int t = 0; t < 2; ++t)
    #pragma unroll
    for (int c = 0; c < 8; ++c)
      w1f[t][c] = *(const short8*)(whh1b + (n0 + t*16 + col)*256 + c*32 + quad*8);
  floatx4 ihcr[2];
  #pragma unroll
  for (int t = 0; t < 2; ++t) {
    float4 iv = *(const float4*)(ihc + (size_t)(bb + col)*256 + n0 + t*16 + quad*4);
    ihcr[t][0] = iv.x; ihcr[t][1] = iv.y; ihcr[t][2] = iv.z; ihcr[t][3] = iv.w;
  }
  #pragma unroll
  for (int t = 0; t < 2; ++t)
    #pragma unroll
    for (int c = 0; c < 8; ++c) asm volatile("" : "+v"(w1f[t][c]));

  {
    int m = tid >> 5, c = tid & 31;
    *(short8*)&hbuf[0][m][c*8] = *(const short8*)(h0bf + (size_t)(bb + m)*256 + c*8);
  }
  __syncthreads();
  #pragma unroll 1
  for (int i = 0; i < 23; ++i) {
    int cur = i & 1;
    floatx4 a1[2];
    #pragma unroll
    for (int t = 0; t < 2; ++t) {
      a1[t][0] = ihcr[t][0]; a1[t][1] = ihcr[t][1];
      a1[t][2] = ihcr[t][2]; a1[t][3] = ihcr[t][3];
    }
    #pragma unroll
    for (int c = 0; c < 8; ++c) {
      short8 hb = *(const short8*)&hbuf[cur][col][c*32 + quad*8];
      a1[0] = __builtin_amdgcn_mfma_f32_16x16x32_bf16(w1f[0][c], hb, a1[0], 0, 0, 0);
      a1[1] = __builtin_amdgcn_mfma_f32_16x16x32_bf16(w1f[1][c], hb, a1[1], 0, 0, 0);
    }
    #pragma unroll
    for (int t = 0; t < 2; ++t) {
      short4_t pk;
      #pragma unroll
      for (int r = 0; r < 4; ++r) pk[r] = f2bf(fast_tanh(a1[t][r]));
      *(short4_t*)&hbuf[cur ^ 1][col][n0 + t*16 + quad*4] = pk;
      *(short4_t*)(hseq + ((size_t)i*512 + bb + col)*256 + n0 + t*16 + quad*4) = pk;
    }
    __syncthreads();
  }
}

// ---------------- fusedB: blocks 0-31 lin_fin, blocks 32-215 y_gemm ------------
__global__ __launch_bounds__(512) void fusedB(
    const short* __restrict__ hseq, const short* __restrict__ wih2b,
    const float* __restrict__ bih2, const float* __restrict__ bhh2,
    float* __restrict__ yseq,
    const float* __restrict__ t1, const float* __restrict__ w_lin2,
    const float* __restrict__ b_lin2, float* __restrict__ outc) {
  __shared__ __align__(16) short As[64][72];
  __shared__ __align__(16) short Bs[256][72];
  __shared__ float st[16][257];
  int tid = threadIdx.x;

  if (blockIdx.x < 32) {
    // ---- lin_fin arm (512 threads) ----
    int bb = blockIdx.x * 16;
    for (int i = tid; i < 4096; i += 512) {
      int m = i >> 8, k = i & 255;
      size_t i0 = (size_t)(bb + m)*256 + k;
      float s = 0.f;
      #pragma unroll
      for (int z = 0; z < 8; ++z) s += t1[i0 + (size_t)z*131072];
      st[m][k] = fast_tanh(s);
    }
    __syncthreads();
    if (tid < 192) {
      int r = tid / 12, j = tid % 12;
      float s = b_lin2[j];
      #pragma unroll 1
      for (int k = 0; k < 256; ++k) s += st[r][k] * w_lin2[j*256 + k];
      outc[(size_t)(bb + r)*12 + j] = s;
    }
    return;
  }

  // ---- y_gemm arm ----
  int lane = tid & 63, w = tid >> 6;
  int quad = lane >> 4, col = lane & 15;
  int m0 = (blockIdx.x - 32) * 64;
  int n0 = w * 32;
  float bv[2];
  #pragma unroll
  for (int t = 0; t < 2; ++t) {
    int n = n0 + t*16 + col;
    bv[t] = bih2[n] + bhh2[n];
  }
  floatx4 acc[4][2];
  #pragma unroll
  for (int ms = 0; ms < 4; ++ms)
    #pragma unroll
    for (int t = 0; t < 2; ++t)
      #pragma unroll
      for (int r = 0; r < 4; ++r) acc[ms][t][r] = bv[t];
  int arow = tid >> 3, achk = tid & 7;
  #pragma unroll 1
  for (int kr = 0; kr < 256; kr += 64) {
    short8 ra = *(const short8*)(hseq + (size_t)(m0 + arow)*256 + kr + achk*8);
    short8 rb[4];
    #pragma unroll
    for (int p = 0; p < 4; ++p) {
      int idx = p*512 + tid;
      rb[p] = *(const short8*)(wih2b + (size_t)(idx >> 3)*256 + kr + (idx & 7)*8);
    }
    if (kr) __syncthreads();
    *(short8*)&As[arow][achk*8] = ra;
    #pragma unroll
    for (int p = 0; p < 4; ++p) {
      int idx = p*512 + tid;
      *(short8*)&Bs[idx >> 3][(idx & 7)*8] = rb[p];
    }
    __syncthreads();
    #pragma unroll
    for (int cc = 0; cc < 2; ++cc) {
      short8 bfr[2];
      #pragma unroll
      for (int t = 0; t < 2; ++t)
        bfr[t] = *(const short8*)&Bs[n0 + t*16 + col][cc*32 + quad*8];
      #pragma unroll
      for (int ms = 0; ms < 4; ++ms) {
        short8 afr = *(const short8*)&As[ms*16 + col][cc*32 + quad*8];
        acc[ms][0] = __builtin_amdgcn_mfma_f32_16x16x32_bf16(afr, bfr[0], acc[ms][0], 0, 0, 0);
        acc[ms][1] = __builtin_amdgcn_mfma_f32_16x16x32_bf16(afr, bfr[1], acc[ms][1], 0, 0, 0);
      }
    }
  }
  #pragma unroll
  for (int ms = 0; ms < 4; ++ms)
    #pragma unroll
    for (int t = 0; t < 2; ++t)
      #pragma unroll
      for (int r = 0; r < 4; ++r)
        yseq[(size_t)(m0 + ms*16 + quad*4 + r)*256 + n0 + t*16 + col] = acc[ms][t][r];
}

// ---------------- t_h2: serial h2-recurrence, whh2 ONLY + precomputed y ---------
__global__ __launch_bounds__(512) void t_h2(
    const float* __restrict__ h2in, const float* __restrict__ yseq,
    const short* __restrict__ whh2b,
    const float* __restrict__ w_fc, const float* __restrict__ b_fc,
    float* __restrict__ preds) {
  __shared__ __align__(16) short h2buf[2][16][264];
  __shared__ float predsAll[23][8][16];
  int tid = threadIdx.x;
  int lane = tid & 63, wid = tid >> 6;
  int quad = lane >> 4, col = lane & 15;
  int bb = blockIdx.x * 16;
  int n0 = wid * 32;
  short8 w3f[2][8];
  #pragma unroll
  for (int t = 0; t < 2; ++t)
    #pragma unroll
    for (int c = 0; c < 8; ++c)
      w3f[t][c] = *(const short8*)(whh2b + (n0 + t*16 + col)*256 + c*32 + quad*8);
  float4 wfcv[2];
  #pragma unroll
  for (int t = 0; t < 2; ++t)
    wfcv[t] = *(const float4*)(w_fc + n0 + t*16 + quad*4);
  float bfc = b_fc[0];
  #pragma unroll
  for (int t = 0; t < 2; ++t)
    #pragma unroll
    for (int c = 0; c < 8; ++c) asm volatile("" : "+v"(w3f[t][c]));

  for (int i = tid; i < 4096; i += 512) {
    int m = i >> 8, k = i & 255;
    h2buf[0][m][k] = f2bf(h2in[(size_t)(bb + m)*256 + k]);
  }
  __syncthreads();
  #pragma unroll 1
  for (int i = 0; i < 23; ++i) {
    int cur = i & 1;
    float4 yv[2];
    #pragma unroll
    for (int t = 0; t < 2; ++t)
      yv[t] = *(const float4*)(yseq + ((size_t)i*512 + bb + col)*256 + n0 + t*16 + quad*4);
    floatx4 z0 = {0.f,0.f,0.f,0.f}, z1 = {0.f,0.f,0.f,0.f};
    #pragma unroll
    for (int c = 0; c < 8; ++c) {
      short8 gb = *(const short8*)&h2buf[cur][col][c*32 + quad*8];
      z0 = __builtin_amdgcn_mfma_f32_16x16x32_bf16(w3f[0][c], gb, z0, 0, 0, 0);
      z1 = __builtin_amdgcn_mfma_f32_16x16x32_bf16(w3f[1][c], gb, z1, 0, 0, 0);
    }
    float pr = 0.f;
    short4_t o0, o1;
    const float* y0p = (const float*)&yv[0];
    const float* y1p = (const float*)&yv[1];
    const float* wf0 = (const float*)&wfcv[0];
    const float* wf1 = (const float*)&wfcv[1];
    #pragma unroll
    for (int r = 0; r < 4; ++r) {
      float t0 = fast_tanh(z0[r] + y0p[r]);
      float t1 = fast_tanh(z1[r] + y1p[r]);
      o0[r] = f2bf(t0); o1[r] = f2bf(t1);
      pr += t0*wf0[r] + t1*wf1[r];
    }
    *(short4_t*)&h2buf[cur ^ 1][col][n0 + quad*4] = o0;
    *(short4_t*)&h2buf[cur ^ 1][col][n0 + 16 + quad*4] = o1;
    pr += __shfl_xor(pr, 16, 64);
    pr += __shfl_xor(pr, 32, 64);
    if (lane < 16) predsAll[i][wid][lane] = pr;
    __syncthreads();
  }
  if (tid < 16) {
    #pragma unroll 1
    for (int p = 0; p < 23; ++p) {
      float sv = bfc;
      #pragma unroll
      for (int w = 0; w < 8; ++w) sv += predsAll[p][w][tid];
      preds[(size_t)(bb + tid)*23 + p] = sv;
    }
  }
}

// ---------------- launch ----------------
extern "C" void kernel_launch(void* const* d_in, const int* in_sizes, int n_in,
                              void* d_out, int out_size, void* d_ws, size_t ws_size,
                              hipStream_t stream) {
  const float* x         = (const float*)d_in[0];
  const float* w1        = (const float*)d_in[1];
  const float* b1        = (const float*)d_in[2];
  const float* w2        = (const float*)d_in[3];
  const float* b2        = (const float*)d_in[4];
  const float* w3        = (const float*)d_in[5];
  const float* b3        = (const float*)d_in[6];
  const float* wih1      = (const float*)d_in[7];
  const float* whh1      = (const float*)d_in[8];
  const float* bih1      = (const float*)d_in[9];
  const float* bhh1      = (const float*)d_in[10];
  const float* wih2      = (const float*)d_in[11];
  const float* whh2      = (const float*)d_in[12];
  const float* bih2      = (const float*)d_in[13];
  const float* bhh2      = (const float*)d_in[14];
  const float* w_init_h  = (const float*)d_in[15];
  const float* b_init_h  = (const float*)d_in[16];
  const float* w_init_h2 = (const float*)d_in[17];
  const float* b_init_h2 = (const float*)d_in[18];
  const float* w_fc      = (const float*)d_in[19];
  const float* b_fc      = (const float*)d_in[20];
  const float* w_lin1    = (const float*)d_in[21];
  const float* b_lin1    = (const float*)d_in[22];
  const float* w_lin2    = (const float*)d_in[23];
  const float* b_lin2    = (const float*)d_in[24];
  float* ws  = (float*)d_ws;
  float* out = (float*)d_out;

  prep_kernel<<<1438, 256, 0, stream>>>(w1, w2, w3, w_init_h, wih1, w_init_h2,
                                        whh1, wih2, whh2, ws);
  conv1_mfma<<<4744, 256, 0, stream>>>(x, (const short*)(ws + OFF_B1P), b1,
                                       (short*)(ws + OFF_P1),
                                       w_lin1, (short*)(ws + OFF_WL1P));
  conv2_mfma<<<1024, 256, 0, stream>>>((const short*)(ws + OFF_P1),
                                       (const short*)(ws + OFF_B2P), b2,
                                       (short*)(ws + OFF_P2));
  conv3_mfma<<<512, 256, 0, stream>>>((const short*)(ws + OFF_P2),
                                      (const short*)(ws + OFF_B3P), b3,
                                      (short*)(ws + OFF_P3BF), ws + OFF_ME);
  init_kernel<<<256, 256, 0, stream>>>(ws + OFF_ME, ws + OFF_WIHT, b_init_h,
                                       ws + OFF_WIH1T, bih1, bhh1,
                                       (short*)(ws + OFF_H0BF), ws + OFF_IHC);
  fusedA<<<168, 512, 0, stream>>>((const short*)(ws + OFF_H0BF), ws + OFF_IHC,
                                  (const short*)(ws + OFF_WHH1B),
                                  (short*)(ws + OFF_HSEQ),
                                  (const short*)(ws + OFF_P3BF),
                                  (const short*)(ws + OFF_WL1P),
                                  b_lin1, ws + OFF_T1,
                                  (const short*)(ws + OFF_WI2B), b_init_h2,
                                  ws + OFF_H2);
  fusedB<<<216, 512, 0, stream>>>((const short*)(ws + OFF_HSEQ),
                                  (const short*)(ws + OFF_WIH2B),
                                  bih2, bhh2, ws + OFF_Y,
                                  ws + OFF_T1, w_lin2, b_lin2, out + 11776);
  t_h2<<<32, 512, 0, stream>>>(ws + OFF_H2, ws + OFF_Y,
                               (const short*)(ws + OFF_WHH2B),
                               w_fc, b_fc, out);
}

// Round 11
// 269.203 us; speedup vs baseline: 1.0864x; 1.0505x over previous
//
#include <hip/hip_runtime.h>
#include <hip/hip_bf16.h>

typedef __attribute__((ext_vector_type(8))) short short8;
typedef __attribute__((ext_vector_type(4))) short short4_t;
typedef __attribute__((ext_vector_type(4))) float floatx4;

// ---------------- workspace layout (float offsets) ----------------
#define OFF_B1P   0        // conv1 B frags [7][64][8] bf16
#define OFF_B2P   1792     // conv2 B frags [2][14][64][8] bf16
#define OFF_B3P   8960     // conv3 B frags [4][27][64][8] bf16
#define OFF_WIHT  36608    // w_init_h^T  (64,256)
#define OFF_WIH1T 52992    // wih1^T      (64,256)
#define OFF_WI2B  69376    // w_init_h2 bf16 row-major [t][k] (reuses old wi2t slot)
#define OFF_WHH1B 134912   // whh1 bf16 row-major [t][k]
#define OFF_WIH2B 167680   // wih2 bf16 row-major
#define OFF_WHH2B 200448   // whh2 bf16 row-major
#define OFF_WL1P  233216   // w_lin1 MFMA frags [nt16][c162][lane64][j8] bf16
#define OFF_ME    896768   // mean_enc (512,64)
#define OFF_H0BF  929536   // h0 bf16 [512][256] (reuses old fp32 h slot)
#define OFF_H2    1060608  // h2_0(512,256) fp32
#define OFF_IHC   1191680  // ih_const (512,256)
#define OFF_P1    1322752  // p1 bf16 [512][1296][16]
#define OFF_T1    1322752  // lin1 partials 8x(512,256) fp32 (over dead p1)
#define OFF_Y     2377728  // y = Hseq@wih2^T + b2, f32 [23*512][256] (over dead p1)
#define OFF_HSEQ  5392384  // h_1..h_23 bf16 [23*512][256] (over dead p1/p2)
#define OFF_P2    6631168  // p2 bf16 [512][324][32]
#define OFF_P3BF  9285376  // p3 bf16 [512][5184]

#define S2_H 88
#define S2_D 1760
#define S3_H 88
#define S3_D 1760
#define S3_HALF 14080

static __device__ inline short f2bf(float f) {
  union { __hip_bfloat16 h; short s; } u;
  u.h = __float2bfloat16(f);
  return u.s;
}
static __device__ inline float bf2f(short s) {
  union { unsigned u; float f; } v;
  v.u = ((unsigned)(unsigned short)s) << 16;
  return v.f;
}
// 5-instr tanh: 1 - 2/(e^{2x}+1); inf-safe both directions
static __device__ inline float fast_tanh(float x) {
  float e = __expf(2.f * x);
  return __builtin_fmaf(-2.f, __builtin_amdgcn_rcpf(e + 1.f), 1.f);
}

// ---------------- prep: weight frag packs + RNN packs ----------------
__global__ __launch_bounds__(256) void prep_kernel(
    const float* __restrict__ w1, const float* __restrict__ w2, const float* __restrict__ w3,
    const float* __restrict__ w_init_h, const float* __restrict__ wih1,
    const float* __restrict__ w_init_h2, const float* __restrict__ whh1,
    const float* __restrict__ wih2, const float* __restrict__ whh2,
    float* __restrict__ ws) {
  int i = blockIdx.x * 256 + threadIdx.x;
  if (i < 3584) {
    int j = i & 7, l = (i >> 3) & 63, c = i >> 9;
    int k = c*32 + ((l >> 4) << 3) + j;
    int tap = k >> 3, icp = k & 7, oc = l & 15;
    float v = (tap < 27 && icp < 6) ? w1[(oc*6 + icp)*27 + tap] : 0.f;
    ((__hip_bfloat16*)(ws + OFF_B1P))[i] = __float2bfloat16(v);
    return;
  }
  i -= 3584;
  if (i < 14336) {
    int j = i & 7, l = (i >> 3) & 63, cc = i >> 9;
    int c = cc % 14, nt = cc / 14;
    int k = c*32 + ((l >> 4) << 3) + j;
    int tap = k >> 4, ic = k & 15, oc = nt*16 + (l & 15);
    float v = (tap < 27) ? w2[(oc*16 + ic)*27 + tap] : 0.f;
    ((__hip_bfloat16*)(ws + OFF_B2P))[i] = __float2bfloat16(v);
    return;
  }
  i -= 14336;
  if (i < 55296) {
    int j = i & 7, l = (i >> 3) & 63, cc = i >> 9;
    int c = cc % 27, nt = cc / 27;
    int k = c*32 + ((l >> 4) << 3) + j;
    int ic = k & 31, oc = nt*16 + (l & 15);
    ((__hip_bfloat16*)(ws + OFF_B3P))[i] = __float2bfloat16(w3[(oc*32 + ic)*27 + c]);
    return;
  }
  i -= 55296;
  if (i < 16384) { int t = i & 255, k = i >> 8; ws[OFF_WIHT + i]  = w_init_h[t*64 + k];  return; }
  i -= 16384;
  if (i < 16384) { int t = i & 255, k = i >> 8; ws[OFF_WIH1T + i] = wih1[t*64 + k];      return; }
  i -= 16384;
  if (i < 65536) { ((__hip_bfloat16*)(ws + OFF_WI2B))[i] = __float2bfloat16(w_init_h2[i]); return; }
  i -= 65536;
  if (i < 65536) { ((__hip_bfloat16*)(ws + OFF_WHH1B))[i] = __float2bfloat16(whh1[i]); return; }
  i -= 65536;
  if (i < 65536) { ((__hip_bfloat16*)(ws + OFF_WIH2B))[i] = __float2bfloat16(wih2[i]); return; }
  i -= 65536;
  if (i < 65536) { ((__hip_bfloat16*)(ws + OFF_WHH2B))[i] = __float2bfloat16(whh2[i]); return; }
}

// ---------------- conv1 MFMA + w_lin1 pack tail blocks ----------------
// R9/R10: occupancy split (hh halves of H) -> 24.3KB slab, 6 blocks/CU.
__global__ __launch_bounds__(256) void conv1_mfma(
    const float* __restrict__ x, const short* __restrict__ b1p,
    const float* __restrict__ bias, short* __restrict__ p1,
    const float* __restrict__ w_lin1, short* __restrict__ wl1p) {
  __shared__ __align__(16) short slab[8 * 38 * 5 * 8];   // 12160 shorts, 24.3KB
  int tid = threadIdx.x;
  if (blockIdx.x >= 4096) {
    int u = (blockIdx.x - 4096)*256 + tid;   // [0, 165888)
    int l = u & 63, cc = u >> 6;
    int c = cc % 162, nt = cc / 162;
    int n = nt*16 + (l & 15);
    int k0 = c*32 + ((l >> 4) << 3);
    const float* src = w_lin1 + (size_t)n*5184 + k0;
    float4 v0 = *(const float4*)src;
    float4 v1 = *(const float4*)(src + 4);
    short8 s;
    s[0] = f2bf(v0.x); s[1] = f2bf(v0.y); s[2] = f2bf(v0.z); s[3] = f2bf(v0.w);
    s[4] = f2bf(v1.x); s[5] = f2bf(v1.y); s[6] = f2bf(v1.z); s[7] = f2bf(v1.w);
    *(short8*)(wl1p + (size_t)u*8) = s;
    return;
  }
  int bq = blockIdx.x >> 1, hh = blockIdx.x & 1;
  int b = bq >> 2, q = bq & 3;
  short8 z8 = {0,0,0,0,0,0,0,0};
  for (int i = tid; i < 1520; i += 256) *(short8*)(slab + i*8) = z8;
  __syncthreads();
  {
    // one staging unit per thread: 8 dslots x 28 float4-groups
    int dslot = tid >> 5, gi = tid & 31;
    if (gi < 28) {
      int g = gi + (hh ? 26 : 0);              // aligned group range per half
      int d = 6*q - 1 + dslot;
      if ((unsigned)d < 24u) {
        float4 v[6];
        #pragma unroll
        for (int ic = 0; ic < 6; ++ic)
          v[ic] = *(const float4*)(x + ((size_t)(b*6 + ic)*24 + d)*216 + g*4);
        const float* vv = (const float*)v;
        int hbase = 36*hh - 1;                 // slab row r = h - hbase
        #pragma unroll
        for (int e = 0; e < 4; ++e) {
          int p = g*4 + e;
          int h = p/3, w = p - h*3;
          int r = h - hbase;
          if ((unsigned)r < 38u) {
            short8 s = z8;
            #pragma unroll
            for (int ic = 0; ic < 6; ++ic) s[ic] = f2bf(vv[ic*4 + e]);
            *(short8*)(slab + (dslot*190 + r*5 + 1 + w)*8) = s;
          }
        }
      }
    }
  }
  int lane = tid & 63, wid = tid >> 6;
  int quad = lane >> 4, col = lane & 15;
  short8 bf[7];
  #pragma unroll
  for (int c = 0; c < 7; ++c) bf[c] = *(const short8*)(b1p + (c*64 + lane)*8);
  int tapslot[7];
  #pragma unroll
  for (int c = 0; c < 7; ++c) {
    int tap = c*4 + quad;
    int tt = tap < 27 ? tap : 26;
    int kd = tt/9, rr = tt - kd*9, kh = rr/3, kw = rr - kh*3;
    tapslot[c] = kd*190 + kh*5 + kw;
  }
  float bv = bias[col];
  __syncthreads();
  for (int tile = wid; tile < 41; tile += 4) {
    int m = tile*16 + col; if (m > 647) m = 647;
    int dd = m & 1, dh = (m >> 1) & 1;
    int P = m >> 2;
    int t2 = P/3; int w = P - t2*3;
    int pdl = t2/18; int ph = t2 - pdl*18;
    int sbase = (2*pdl + dd)*190 + (2*ph + dh)*5 + w;
    floatx4 acc = {0.f, 0.f, 0.f, 0.f};
    #pragma unroll
    for (int c = 0; c < 7; ++c) {
      short8 af = *(const short8*)(slab + (sbase + tapslot[c])*8);
      acc = __builtin_amdgcn_mfma_f32_16x16x32_bf16(af, bf[c], acc, 0, 0, 0);
    }
    float v = fmaxf(fmaxf(acc[0], acc[1]), fmaxf(acc[2], acc[3]));
    v = fmaxf(v + bv, 0.f);
    int Pl = tile*4 + quad;
    if (Pl < 162) {
      int t2o = Pl/3; int wo = Pl - t2o*3;
      int pdo = t2o/18; int pho = t2o - pdo*18;
      int Pout = q*324 + hh*54 + pdo*108 + pho*3 + wo;
      p1[((size_t)b*1296 + Pout)*16 + col] = f2bf(v);
    }
  }
}

// ---------------- conv2 MFMA, halo slab: p1 -> p2 bf16 [b][324][32] ----------------
// R11: occupancy split by output-d (qd halves). Slab 8 d-slots x 20 h x 88 =
// 14080 shorts = 28.2KB -> 5 blocks/CU (was 49.3KB -> 3). Tap slot algebra:
// global slot 2*pd+dd+kd -> local 2*pdl+dd+kd with pd = 3*qd+pdl (constants
// S2_D/S2_H unchanged); d-halo handled by zero-fill + dg bounds check.
__global__ __launch_bounds__(256) void conv2_mfma(
    const short* __restrict__ p1, const short* __restrict__ b2p,
    const float* __restrict__ bias2, short* __restrict__ p2g) {
  __shared__ __align__(16) short slab[8 * S2_D];   // 14080 shorts
  int tid = threadIdx.x;
  int b = blockIdx.x >> 2, qd = (blockIdx.x >> 1) & 1, qh = blockIdx.x & 1;
  short8 z8 = {0,0,0,0,0,0,0,0};
  for (int i = tid; i < 1760; i += 256) *(short8*)(slab + i*8) = z8;
  __syncthreads();
  for (int i = tid; i < 960; i += 256) {
    int c8 = i % 6; int r = i / 6; int hr = r % 20; int dslot = r / 20;
    int hg = 18*qh - 1 + hr;
    int dg = 6*qd - 1 + dslot;
    if ((unsigned)hg < 36u && (unsigned)dg < 12u) {
      short8 v = *(const short8*)(p1 + ((size_t)b*1296 + (dg*36 + hg)*3)*16 + c8*8);
      *(short8*)(slab + dslot*S2_D + hr*S2_H + 16 + c8*8) = v;
    }
  }
  int lane = tid & 63, wid = tid >> 6;
  int quad = lane >> 4, col = lane & 15;
  short8 bf[2][14];
  #pragma unroll
  for (int nt = 0; nt < 2; ++nt)
    #pragma unroll
    for (int c = 0; c < 14; ++c)
      bf[nt][c] = *(const short8*)(b2p + ((nt*14 + c)*64 + lane)*8);
  int tq = quad >> 1, icoff = (quad & 1) * 8;
  int tapoff[14];
  #pragma unroll
  for (int c = 0; c < 14; ++c) {
    int tap = 2*c + tq; if (tap > 26) tap = 26;
    int kd = tap/9, rr = tap - kd*9, kh = rr/3, kw = rr - kh*3;
    tapoff[c] = kd*S2_D + kh*S2_H + kw*16 + icoff;
  }
  float bv0 = bias2[col], bv1 = bias2[16 + col];
  __syncthreads();
  for (int tile = wid; tile < 21; tile += 4) {
    int m = tile*16 + col; if (m > 323) m = 323;
    int dd = m & 1, dh = (m >> 1) & 1;
    int P = m >> 2;                       // 0..80
    int t = P/3; int w = P - t*3;         // t 0..26
    int pdl = t/9; int phl = t - pdl*9;   // pdl 0..2, phl 0..8
    int base = (2*pdl + dd)*S2_D + (2*phl + dh)*S2_H + w*16;
    floatx4 a0 = {0.f,0.f,0.f,0.f}, a1 = {0.f,0.f,0.f,0.f};
    #pragma unroll
    for (int c = 0; c < 14; ++c) {
      short8 a = *(const short8*)(slab + base + tapoff[c]);
      a0 = __builtin_amdgcn_mfma_f32_16x16x32_bf16(a, bf[0][c], a0, 0, 0, 0);
      a1 = __builtin_amdgcn_mfma_f32_16x16x32_bf16(a, bf[1][c], a1, 0, 0, 0);
    }
    int P2l = tile*4 + quad;
    if (P2l < 81) {
      float v0 = fmaxf(fmaxf(fmaxf(a0[0],a0[1]), fmaxf(a0[2],a0[3])) + bv0, 0.f);
      float v1 = fmaxf(fmaxf(fmaxf(a1[0],a1[1]), fmaxf(a1[2],a1[3])) + bv1, 0.f);
      int t2 = P2l/3; int w2 = P2l - t2*3;
      int pdl2 = t2/9; int ph2 = t2 - pdl2*9;
      int pd2 = pdl2 + 3*qd;
      size_t off = ((size_t)b*324 + (pd2*18 + 9*qh + ph2)*3 + w2)*32;
      p2g[off + col] = f2bf(v0);
      p2g[off + 16 + col] = f2bf(v1);
    }
  }
}

// ---------------- conv3 MFMA, dual ic-half halo slabs: p2 -> p3bf + mean ----------------
__global__ __launch_bounds__(256) void conv3_mfma(
    const short* __restrict__ p2g, const short* __restrict__ b3p,
    const float* __restrict__ bias3,
    short* __restrict__ p3bf, float* __restrict__ me) {
  __shared__ __align__(16) short slab[2 * S3_HALF];
  __shared__ float smean[4][32];
  int tid = threadIdx.x;
  int b = blockIdx.x;
  short8 z8 = {0,0,0,0,0,0,0,0};
  for (int i = tid; i < 3520; i += 256) *(short8*)(slab + i*8) = z8;
  __syncthreads();
  for (int i = tid; i < 1296; i += 256) {
    int c8 = i & 1;
    int hv = (i >> 1) & 1;
    int cell = i >> 2;
    int t = cell/3; int w = cell - t*3;
    int d = t/18; int h = t - d*18;
    short8 v = *(const short8*)(p2g + ((size_t)b*324 + cell)*32 + hv*16 + c8*8);
    *(short8*)(slab + hv*S3_HALF + (d+1)*S3_D + (h+1)*S3_H + (w+1)*16 + c8*8) = v;
  }
  int lane = tid & 63, wid = tid >> 6;
  int quad = lane >> 4, col = lane & 15;
  int ntp = (wid & 1) * 2;
  int tsel = wid >> 1;
  short8 bf[2][27];
  #pragma unroll
  for (int u = 0; u < 2; ++u)
    #pragma unroll
    for (int c = 0; c < 27; ++c)
      bf[u][c] = *(const short8*)(b3p + (((ntp+u)*27 + c)*64 + lane)*8);
  const short* sb = slab + (quad >> 1)*S3_HALF + (quad & 1)*8;
  float bva = bias3[ntp*16 + col], bvb = bias3[(ntp+1)*16 + col];
  float ms0 = 0.f, ms1 = 0.f;
  __syncthreads();
  for (int tile = tsel; tile < 21; tile += 2) {
    int m = tile*16 + col; if (m > 323) m = 323;
    int dd = m & 1, dh = (m >> 1) & 1;
    int P = m >> 2;
    int t = P/3; int w = P - t*3;
    int pd = t/9; int ph = t - pd*9;
    const short* ap = sb + (2*pd + dd)*S3_D + (2*ph + dh)*S3_H + w*16;
    floatx4 a0 = {0.f,0.f,0.f,0.f}, a1 = {0.f,0.f,0.f,0.f};
    #pragma unroll
    for (int c = 0; c < 27; ++c) {
      const int kd = c/9, rr = c - kd*9, kh = rr/3, kw = rr - kh*3;
      short8 a = *(const short8*)(ap + kd*S3_D + kh*S3_H + kw*16);
      a0 = __builtin_amdgcn_mfma_f32_16x16x32_bf16(a, bf[0][c], a0, 0, 0, 0);
      a1 = __builtin_amdgcn_mfma_f32_16x16x32_bf16(a, bf[1][c], a1, 0, 0, 0);
    }
    int Pout = tile*4 + quad;
    if (Pout < 81) {
      float v0 = fmaxf(fmaxf(fmaxf(a0[0],a0[1]), fmaxf(a0[2],a0[3])) + bva, 0.f);
      float v1 = fmaxf(fmaxf(fmaxf(a1[0],a1[1]), fmaxf(a1[2],a1[3])) + bvb, 0.f);
      size_t oi = ((size_t)b*81 + Pout)*64 + ntp*16 + col;
      p3bf[oi] = f2bf(v0);
      p3bf[oi + 16] = f2bf(v1);
      ms0 += v0; ms1 += v1;
    }
  }
  ms0 += __shfl_xor(ms0, 16, 64); ms0 += __shfl_xor(ms0, 32, 64);
  ms1 += __shfl_xor(ms1, 16, 64); ms1 += __shfl_xor(ms1, 32, 64);
  if (lane < 16) { smean[wid][lane] = ms0; smean[wid][16 + lane] = ms1; }
  __syncthreads();
  if (tid < 64) {
    float s = (tid < 32) ? (smean[0][tid] + smean[2][tid])
                         : (smean[1][tid-32] + smean[3][tid-32]);
    me[b*64 + tid] = s * (1.f / 81.f);
  }
}

// ---------------- init: h0 (bf16) + ihc only; K=64. 256 blocks x 2 rows -------
__global__ __launch_bounds__(256) void init_kernel(
    const float* __restrict__ me, const float* __restrict__ wiht,
    const float* __restrict__ b_init_h, const float* __restrict__ wih1t,
    const float* __restrict__ bih1, const float* __restrict__ bhh1,
    short* __restrict__ h0bf, float* __restrict__ ihcout) {
  __shared__ float sme[2][64];
  int t = threadIdx.x; int bb = blockIdx.x * 2;
  if (t < 128) sme[t >> 6][t & 63] = me[(bb + (t >> 6))*64 + (t & 63)];
  __syncthreads();
  float a0 = b_init_h[t], a1 = a0;
  float c0 = bih1[t] + bhh1[t], c1 = c0;
  #pragma unroll
  for (int k = 0; k < 64; ++k) {
    float w1v = wiht[k*256 + t], w2v = wih1t[k*256 + t];
    a0 += sme[0][k]*w1v; a1 += sme[1][k]*w1v;
    c0 += sme[0][k]*w2v; c1 += sme[1][k]*w2v;
  }
  h0bf[(size_t)bb*256 + t]     = f2bf(a0);
  h0bf[(size_t)(bb+1)*256 + t] = f2bf(a1);
  ihcout[(size_t)bb*256 + t]     = c0;
  ihcout[(size_t)(bb+1)*256 + t] = c1;
}

// ---------------- fusedA: blocks 0-31 t_h, 32-159 lin1, 160-167 h2_0 GEMM -----
__global__ __launch_bounds__(512) void fusedA(
    const short* __restrict__ h0bf, const float* __restrict__ ihc,
    const short* __restrict__ whh1b, short* __restrict__ hseq,
    const short* __restrict__ p3bf, const short* __restrict__ wl1p,
    const float* __restrict__ b_lin1, float* __restrict__ t1,
    const short* __restrict__ wi2b, const float* __restrict__ b_init_h2,
    float* __restrict__ h2out) {
  __shared__ __align__(16) short pool[23040];
  int tid = threadIdx.x;

  if (blockIdx.x >= 160) {
    // ---- h2_0 arm: 64 rows x 256 cols, K=256 ----
    short (*As)[72] = (short (*)[72])pool;              // [64][72]
    short (*Bs)[72] = (short (*)[72])(pool + 4608);     // [256][72]
    int lane = tid & 63, w = tid >> 6;
    int quad = lane >> 4, col = lane & 15;
    int m0 = (blockIdx.x - 160) * 64;
    int n0 = w * 32;
    float bv[2];
    #pragma unroll
    for (int t = 0; t < 2; ++t) bv[t] = b_init_h2[n0 + t*16 + col];
    floatx4 acc[4][2];
    #pragma unroll
    for (int ms = 0; ms < 4; ++ms)
      #pragma unroll
      for (int t = 0; t < 2; ++t)
        #pragma unroll
        for (int r = 0; r < 4; ++r) acc[ms][t][r] = bv[t];
    int arow = tid >> 3, achk = tid & 7;
    #pragma unroll 1
    for (int kr = 0; kr < 256; kr += 64) {
      short8 ra = *(const short8*)(h0bf + (size_t)(m0 + arow)*256 + kr + achk*8);
      short8 rb[4];
      #pragma unroll
      for (int p = 0; p < 4; ++p) {
        int idx = p*512 + tid;
        rb[p] = *(const short8*)(wi2b + (size_t)(idx >> 3)*256 + kr + (idx & 7)*8);
      }
      if (kr) __syncthreads();
      *(short8*)&As[arow][achk*8] = ra;
      #pragma unroll
      for (int p = 0; p < 4; ++p) {
        int idx = p*512 + tid;
        *(short8*)&Bs[idx >> 3][(idx & 7)*8] = rb[p];
      }
      __syncthreads();
      #pragma unroll
      for (int cc = 0; cc < 2; ++cc) {
        short8 bfr[2];
        #pragma unroll
        for (int t = 0; t < 2; ++t)
          bfr[t] = *(const short8*)&Bs[n0 + t*16 + col][cc*32 + quad*8];
        #pragma unroll
        for (int ms = 0; ms < 4; ++ms) {
          short8 afr = *(const short8*)&As[ms*16 + col][cc*32 + quad*8];
          acc[ms][0] = __builtin_amdgcn_mfma_f32_16x16x32_bf16(afr, bfr[0], acc[ms][0], 0, 0, 0);
          acc[ms][1] = __builtin_amdgcn_mfma_f32_16x16x32_bf16(afr, bfr[1], acc[ms][1], 0, 0, 0);
        }
      }
    }
    #pragma unroll
    for (int ms = 0; ms < 4; ++ms)
      #pragma unroll
      for (int t = 0; t < 2; ++t)
        #pragma unroll
        for (int r = 0; r < 4; ++r)
          h2out[(size_t)(m0 + ms*16 + quad*4 + r)*256 + n0 + t*16 + col] = acc[ms][t][r];
    return;
  }

  if (blockIdx.x >= 32) {
    // ---- lin1 arm ----
    short (*Ab)[512][8] = (short (*)[512][8])pool;
    short (*Bb)[512][8] = (short (*)[512][8])(pool + 8192);
    int sub = tid >> 8, stid = tid & 255;
    int lane = stid & 63, w = stid >> 6;
    int quad = lane >> 4, col = lane & 15;
    int idx = (blockIdx.x - 32)*2 + sub;   // [0,256)
    int mt = idx & 7, ntb = (idx >> 3) & 3, kz = idx >> 5;
    int c0 = (kz <= 2) ? kz*22 : 44 + (kz - 2)*20;
    int cn = (kz < 2) ? 22 : ((kz == 7) ? 18 : 20);
    int Nr = cn >> 1;
    int m0 = mt*64;
    floatx4 acc[4];
    #pragma unroll
    for (int t = 0; t < 4; ++t) {
      float bv = (kz == 0) ? b_lin1[ntb*64 + t*16 + col] : 0.f;
      #pragma unroll
      for (int r = 0; r < 4; ++r) acc[t][r] = bv;
    }
    const short* asrc = p3bf + (size_t)(m0 + w*16 + col)*5184 + c0*32 + quad*8;
    const short* bsrc = wl1p + ((size_t)((ntb*4 + w)*162 + c0)*64 + lane)*8;
    short8 ra0 = *(const short8*)asrc;
    short8 ra1 = *(const short8*)(asrc + 32);
    short8 rb0 = *(const short8*)bsrc;
    short8 rb1 = *(const short8*)(bsrc + 512);
    asrc += 64; bsrc += 1024;
    #pragma unroll 1
    for (int r = 0; r < Nr; ++r) {
      *(short8*)&Ab[0][tid][0] = ra0;
      *(short8*)&Ab[1][tid][0] = ra1;
      *(short8*)&Bb[0][tid][0] = rb0;
      *(short8*)&Bb[1][tid][0] = rb1;
      if (r + 1 < Nr) {
        ra0 = *(const short8*)asrc;
        ra1 = *(const short8*)(asrc + 32);
        rb0 = *(const short8*)bsrc;
        rb1 = *(const short8*)(bsrc + 512);
        asrc += 64; bsrc += 1024;
      }
      __syncthreads();
      #pragma unroll
      for (int cc = 0; cc < 2; ++cc) {
        short8 a = *(const short8*)&Ab[cc][sub*256 + w*64 + lane][0];
        #pragma unroll
        for (int t = 0; t < 4; ++t) {
          short8 b = *(const short8*)&Bb[cc][sub*256 + t*64 + lane][0];
          acc[t] = __builtin_amdgcn_mfma_f32_16x16x32_bf16(a, b, acc[t], 0, 0, 0);
        }
      }
      __syncthreads();
    }
    float* to = t1 + (size_t)kz * 131072;
    #pragma unroll
    for (int t = 0; t < 4; ++t)
      #pragma unroll
      for (int r = 0; r < 4; ++r)
        to[(size_t)(m0 + w*16 + quad*4 + r)*256 + ntb*64 + t*16 + col] = acc[t][r];
    return;
  }

  // ---- t_h arm ----
  short (*hbuf)[16][264] = (short (*)[16][264])pool;
  int lane = tid & 63, wid = tid >> 6;
  int quad = lane >> 4, col = lane & 15;
  int bb = blockIdx.x * 16;
  int n0 = wid * 32;
  short8 w1f[2][8];
  #pragma unroll
  for (int t = 0; t < 2; ++t)
    #pragma unroll
    for (int c = 0; c < 8; ++c)
      w1f[t][c] = *(const short8*)(whh1b + (n0 + t*16 + col)*256 + c*32 + quad*8);
  floatx4 ihcr[2];
  #pragma unroll
  for (int t = 0; t < 2; ++t) {
    float4 iv = *(const float4*)(ihc + (size_t)(bb + col)*256 + n0 + t*16 + quad*4);
    ihcr[t][0] = iv.x; ihcr[t][1] = iv.y; ihcr[t][2] = iv.z; ihcr[t][3] = iv.w;
  }
  #pragma unroll
  for (int t = 0; t < 2; ++t)
    #pragma unroll
    for (int c = 0; c < 8; ++c) asm volatile("" : "+v"(w1f[t][c]));

  {
    int m = tid >> 5, c = tid & 31;
    *(short8*)&hbuf[0][m][c*8] = *(const short8*)(h0bf + (size_t)(bb + m)*256 + c*8);
  }
  __syncthreads();
  #pragma unroll 1
  for (int i = 0; i < 23; ++i) {
    int cur = i & 1;
    floatx4 a1[2];
    #pragma unroll
    for (int t = 0; t < 2; ++t) {
      a1[t][0] = ihcr[t][0]; a1[t][1] = ihcr[t][1];
      a1[t][2] = ihcr[t][2]; a1[t][3] = ihcr[t][3];
    }
    #pragma unroll
    for (int c = 0; c < 8; ++c) {
      short8 hb = *(const short8*)&hbuf[cur][col][c*32 + quad*8];
      a1[0] = __builtin_amdgcn_mfma_f32_16x16x32_bf16(w1f[0][c], hb, a1[0], 0, 0, 0);
      a1[1] = __builtin_amdgcn_mfma_f32_16x16x32_bf16(w1f[1][c], hb, a1[1], 0, 0, 0);
    }
    #pragma unroll
    for (int t = 0; t < 2; ++t) {
      short4_t pk;
      #pragma unroll
      for (int r = 0; r < 4; ++r) pk[r] = f2bf(fast_tanh(a1[t][r]));
      *(short4_t*)&hbuf[cur ^ 1][col][n0 + t*16 + quad*4] = pk;
      *(short4_t*)(hseq + ((size_t)i*512 + bb + col)*256 + n0 + t*16 + quad*4) = pk;
    }
    __syncthreads();
  }
}

// ---------------- fusedB: blocks 0-31 lin_fin, blocks 32-215 y_gemm ------------
// R11 lin_fin fix: the k-loop read w_lin2 from global with '#pragma unroll 1'
// (serial L2-latency chain, ~8-15us at 12.5% chip). w_lin2 is 12KB -> stage
// into LDS once (padded [12][260]: j and j+8 share a bank = free 2-way),
// unroll 8. LDS pooled (union) -> fusedB block LDS 62.5KB -> 46KB.
__global__ __launch_bounds__(512) void fusedB(
    const short* __restrict__ hseq, const short* __restrict__ wih2b,
    const float* __restrict__ bih2, const float* __restrict__ bhh2,
    float* __restrict__ yseq,
    const float* __restrict__ t1, const float* __restrict__ w_lin2,
    const float* __restrict__ b_lin2, float* __restrict__ outc) {
  __shared__ __align__(16) unsigned char poolB[46080];
  int tid = threadIdx.x;

  if (blockIdx.x < 32) {
    // ---- lin_fin arm (512 threads) ----
    float (*st)[257] = (float (*)[257])poolB;          // 16*257*4 = 16448 B
    float* swl = (float*)(poolB + 16448);              // 12*260*4 = 12480 B
    int bb = blockIdx.x * 16;
    for (int i = tid; i < 3072; i += 512) {
      int j = i >> 8, k = i & 255;
      swl[j*260 + k] = w_lin2[i];
    }
    for (int i = tid; i < 4096; i += 512) {
      int m = i >> 8, k = i & 255;
      size_t i0 = (size_t)(bb + m)*256 + k;
      float s = 0.f;
      #pragma unroll
      for (int z = 0; z < 8; ++z) s += t1[i0 + (size_t)z*131072];
      st[m][k] = fast_tanh(s);
    }
    __syncthreads();
    if (tid < 192) {
      int r = tid / 12, j = tid % 12;
      float s = b_lin2[j];
      #pragma unroll 8
      for (int k = 0; k < 256; ++k) s += st[r][k] * swl[j*260 + k];
      outc[(size_t)(bb + r)*12 + j] = s;
    }
    return;
  }

  // ---- y_gemm arm ----
  short (*As)[72] = (short (*)[72])poolB;              // 64*72*2  = 9216 B
  short (*Bs)[72] = (short (*)[72])(poolB + 9216);     // 256*72*2 = 36864 B
  int lane = tid & 63, w = tid >> 6;
  int quad = lane >> 4, col = lane & 15;
  int m0 = (blockIdx.x - 32) * 64;
  int n0 = w * 32;
  float bv[2];
  #pragma unroll
  for (int t = 0; t < 2; ++t) {
    int n = n0 + t*16 + col;
    bv[t] = bih2[n] + bhh2[n];
  }
  floatx4 acc[4][2];
  #pragma unroll
  for (int ms = 0; ms < 4; ++ms)
    #pragma unroll
    for (int t = 0; t < 2; ++t)
      #pragma unroll
      for (int r = 0; r < 4; ++r) acc[ms][t][r] = bv[t];
  int arow = tid >> 3, achk = tid & 7;
  #pragma unroll 1
  for (int kr = 0; kr < 256; kr += 64) {
    short8 ra = *(const short8*)(hseq + (size_t)(m0 + arow)*256 + kr + achk*8);
    short8 rb[4];
    #pragma unroll
    for (int p = 0; p < 4; ++p) {
      int idx = p*512 + tid;
      rb[p] = *(const short8*)(wih2b + (size_t)(idx >> 3)*256 + kr + (idx & 7)*8);
    }
    if (kr) __syncthreads();
    *(short8*)&As[arow][achk*8] = ra;
    #pragma unroll
    for (int p = 0; p < 4; ++p) {
      int idx = p*512 + tid;
      *(short8*)&Bs[idx >> 3][(idx & 7)*8] = rb[p];
    }
    __syncthreads();
    #pragma unroll
    for (int cc = 0; cc < 2; ++cc) {
      short8 bfr[2];
      #pragma unroll
      for (int t = 0; t < 2; ++t)
        bfr[t] = *(const short8*)&Bs[n0 + t*16 + col][cc*32 + quad*8];
      #pragma unroll
      for (int ms = 0; ms < 4; ++ms) {
        short8 afr = *(const short8*)&As[ms*16 + col][cc*32 + quad*8];
        acc[ms][0] = __builtin_amdgcn_mfma_f32_16x16x32_bf16(afr, bfr[0], acc[ms][0], 0, 0, 0);
        acc[ms][1] = __builtin_amdgcn_mfma_f32_16x16x32_bf16(afr, bfr[1], acc[ms][1], 0, 0, 0);
      }
    }
  }
  #pragma unroll
  for (int ms = 0; ms < 4; ++ms)
    #pragma unroll
    for (int t = 0; t < 2; ++t)
      #pragma unroll
      for (int r = 0; r < 4; ++r)
        yseq[(size_t)(m0 + ms*16 + quad*4 + r)*256 + n0 + t*16 + col] = acc[ms][t][r];
}

// ---------------- t_h2: serial h2-recurrence, whh2 ONLY + precomputed y ---------
__global__ __launch_bounds__(512) void t_h2(
    const float* __restrict__ h2in, const float* __restrict__ yseq,
    const short* __restrict__ whh2b,
    const float* __restrict__ w_fc, const float* __restrict__ b_fc,
    float* __restrict__ preds) {
  __shared__ __align__(16) short h2buf[2][16][264];
  __shared__ float predsAll[23][8][16];
  int tid = threadIdx.x;
  int lane = tid & 63, wid = tid >> 6;
  int quad = lane >> 4, col = lane & 15;
  int bb = blockIdx.x * 16;
  int n0 = wid * 32;
  short8 w3f[2][8];
  #pragma unroll
  for (int t = 0; t < 2; ++t)
    #pragma unroll
    for (int c = 0; c < 8; ++c)
      w3f[t][c] = *(const short8*)(whh2b + (n0 + t*16 + col)*256 + c*32 + quad*8);
  float4 wfcv[2];
  #pragma unroll
  for (int t = 0; t < 2; ++t)
    wfcv[t] = *(const float4*)(w_fc + n0 + t*16 + quad*4);
  float bfc = b_fc[0];
  #pragma unroll
  for (int t = 0; t < 2; ++t)
    #pragma unroll
    for (int c = 0; c < 8; ++c) asm volatile("" : "+v"(w3f[t][c]));

  for (int i = tid; i < 4096; i += 512) {
    int m = i >> 8, k = i & 255;
    h2buf[0][m][k] = f2bf(h2in[(size_t)(bb + m)*256 + k]);
  }
  __syncthreads();
  #pragma unroll 1
  for (int i = 0; i < 23; ++i) {
    int cur = i & 1;
    float4 yv[2];
    #pragma unroll
    for (int t = 0; t < 2; ++t)
      yv[t] = *(const float4*)(yseq + ((size_t)i*512 + bb + col)*256 + n0 + t*16 + quad*4);
    floatx4 z0 = {0.f,0.f,0.f,0.f}, z1 = {0.f,0.f,0.f,0.f};
    #pragma unroll
    for (int c = 0; c < 8; ++c) {
      short8 gb = *(const short8*)&h2buf[cur][col][c*32 + quad*8];
      z0 = __builtin_amdgcn_mfma_f32_16x16x32_bf16(w3f[0][c], gb, z0, 0, 0, 0);
      z1 = __builtin_amdgcn_mfma_f32_16x16x32_bf16(w3f[1][c], gb, z1, 0, 0, 0);
    }
    float pr = 0.f;
    short4_t o0, o1;
    const float* y0p = (const float*)&yv[0];
    const float* y1p = (const float*)&yv[1];
    const float* wf0 = (const float*)&wfcv[0];
    const float* wf1 = (const float*)&wfcv[1];
    #pragma unroll
    for (int r = 0; r < 4; ++r) {
      float t0 = fast_tanh(z0[r] + y0p[r]);
      float t1 = fast_tanh(z1[r] + y1p[r]);
      o0[r] = f2bf(t0); o1[r] = f2bf(t1);
      pr += t0*wf0[r] + t1*wf1[r];
    }
    *(short4_t*)&h2buf[cur ^ 1][col][n0 + quad*4] = o0;
    *(short4_t*)&h2buf[cur ^ 1][col][n0 + 16 + quad*4] = o1;
    pr += __shfl_xor(pr, 16, 64);
    pr += __shfl_xor(pr, 32, 64);
    if (lane < 16) predsAll[i][wid][lane] = pr;
    __syncthreads();
  }
  if (tid < 16) {
    #pragma unroll 1
    for (int p = 0; p < 23; ++p) {
      float sv = bfc;
      #pragma unroll
      for (int w = 0; w < 8; ++w) sv += predsAll[p][w][tid];
      preds[(size_t)(bb + tid)*23 + p] = sv;
    }
  }
}

// ---------------- launch ----------------
extern "C" void kernel_launch(void* const* d_in, const int* in_sizes, int n_in,
                              void* d_out, int out_size, void* d_ws, size_t ws_size,
                              hipStream_t stream) {
  const float* x         = (const float*)d_in[0];
  const float* w1        = (const float*)d_in[1];
  const float* b1        = (const float*)d_in[2];
  const float* w2        = (const float*)d_in[3];
  const float* b2        = (const float*)d_in[4];
  const float* w3        = (const float*)d_in[5];
  const float* b3        = (const float*)d_in[6];
  const float* wih1      = (const float*)d_in[7];
  const float* whh1      = (const float*)d_in[8];
  const float* bih1      = (const float*)d_in[9];
  const float* bhh1      = (const float*)d_in[10];
  const float* wih2      = (const float*)d_in[11];
  const float* whh2      = (const float*)d_in[12];
  const float* bih2      = (const float*)d_in[13];
  const float* bhh2      = (const float*)d_in[14];
  const float* w_init_h  = (const float*)d_in[15];
  const float* b_init_h  = (const float*)d_in[16];
  const float* w_init_h2 = (const float*)d_in[17];
  const float* b_init_h2 = (const float*)d_in[18];
  const float* w_fc      = (const float*)d_in[19];
  const float* b_fc      = (const float*)d_in[20];
  const float* w_lin1    = (const float*)d_in[21];
  const float* b_lin1    = (const float*)d_in[22];
  const float* w_lin2    = (const float*)d_in[23];
  const float* b_lin2    = (const float*)d_in[24];
  float* ws  = (float*)d_ws;
  float* out = (float*)d_out;

  prep_kernel<<<1438, 256, 0, stream>>>(w1, w2, w3, w_init_h, wih1, w_init_h2,
                                        whh1, wih2, whh2, ws);
  conv1_mfma<<<4744, 256, 0, stream>>>(x, (const short*)(ws + OFF_B1P), b1,
                                       (short*)(ws + OFF_P1),
                                       w_lin1, (short*)(ws + OFF_WL1P));
  conv2_mfma<<<2048, 256, 0, stream>>>((const short*)(ws + OFF_P1),
                                       (const short*)(ws + OFF_B2P), b2,
                                       (short*)(ws + OFF_P2));
  conv3_mfma<<<512, 256, 0, stream>>>((const short*)(ws + OFF_P2),
                                      (const short*)(ws + OFF_B3P), b3,
                                      (short*)(ws + OFF_P3BF), ws + OFF_ME);
  init_kernel<<<256, 256, 0, stream>>>(ws + OFF_ME, ws + OFF_WIHT, b_init_h,
                                       ws + OFF_WIH1T, bih1, bhh1,
                                       (short*)(ws + OFF_H0BF), ws + OFF_IHC);
  fusedA<<<168, 512, 0, stream>>>((const short*)(ws + OFF_H0BF), ws + OFF_IHC,
                                  (const short*)(ws + OFF_WHH1B),
                                  (short*)(ws + OFF_HSEQ),
                                  (const short*)(ws + OFF_P3BF),
                                  (const short*)(ws + OFF_WL1P),
                                  b_lin1, ws + OFF_T1,
                                  (const short*)(ws + OFF_WI2B), b_init_h2,
                                  ws + OFF_H2);
  fusedB<<<216, 512, 0, stream>>>((const short*)(ws + OFF_HSEQ),
                                  (const short*)(ws + OFF_WIH2B),
                                  bih2, bhh2, ws + OFF_Y,
                                  ws + OFF_T1, w_lin2, b_lin2, out + 11776);
  t_h2<<<32, 512, 0, stream>>>(ws + OFF_H2, ws + OFF_Y,
                               (const short*)(ws + OFF_WHH2B),
                               w_fc, b_fc, out);
}